// Round 1
// baseline (319.864 us; speedup 1.0000x reference)
//
#include <hip/hip_runtime.h>
#include <hip/hip_bf16.h>
#include <stdint.h>
#include <stddef.h>

// MHA forward, B=2 S=2048 D=1024 H=16 Dh=64, bf16 MFMA pipeline.
// Stages: cvt(fp32->bf16) -> proj QKV (NT GEMM, V stored transposed per head)
//         -> flash attention (online softmax) -> output proj (fp32 out).

typedef __attribute__((ext_vector_type(8))) short short8;   // 8 x bf16 (4 VGPR)
typedef __attribute__((ext_vector_type(4))) float f32x4;    // MFMA C/D
typedef __attribute__((ext_vector_type(4))) unsigned short usv4;

#define DEVFN static __device__ __forceinline__

constexpr float LOG2E = 1.44269504088896340736f;

DEVFN f32x4 mfma16(short8 a, short8 b, f32x4 c) {
  return __builtin_amdgcn_mfma_f32_16x16x32_bf16(a, b, c, 0, 0, 0);
}

// async global->LDS, 16B per lane. Dest must be linear in lane id.
DEVFN void gload_lds16(const void* g, void* l) {
  __builtin_amdgcn_global_load_lds(
      (const __attribute__((address_space(1))) unsigned int*)g,
      (__attribute__((address_space(3))) unsigned int*)l, 16, 0, 0);
}

DEVFN unsigned short f2bf(float x) {
  union { __hip_bfloat16 h; unsigned short u; } cv;
  cv.h = __float2bfloat16(x);
  return cv.u;
}

DEVFN short8 cvt8(const float* s) {
  float4 a = *(const float4*)(s);
  float4 b = *(const float4*)(s + 4);
  short8 o;
  o[0] = (short)f2bf(a.x); o[1] = (short)f2bf(a.y);
  o[2] = (short)f2bf(a.z); o[3] = (short)f2bf(a.w);
  o[4] = (short)f2bf(b.x); o[5] = (short)f2bf(b.y);
  o[6] = (short)f2bf(b.z); o[7] = (short)f2bf(b.w);
  return o;
}

// ---------------- fp32 -> bf16 conversion ----------------

__global__ __launch_bounds__(256) void cvt_inputs(
    const float* __restrict__ s0, const float* __restrict__ s1,
    const float* __restrict__ s2, __hip_bfloat16* __restrict__ dst) {
  const int y = blockIdx.y;
  const float* s = (y == 0) ? s0 : ((y == 1) ? s1 : s2);
  __hip_bfloat16* d = dst + (size_t)y * (4096u * 1024u);
  const size_t i = ((size_t)blockIdx.x * 256 + threadIdx.x) * 8;
  *(short8*)(d + i) = cvt8(s + i);
}

__global__ __launch_bounds__(256) void cvt_weights(
    const float* __restrict__ s0, const float* __restrict__ s1,
    const float* __restrict__ s2, const float* __restrict__ s3,
    __hip_bfloat16* __restrict__ dst) {
  const int y = blockIdx.y;
  const float* s = (y == 0) ? s0 : (y == 1) ? s1 : (y == 2) ? s2 : s3;
  __hip_bfloat16* d = dst + (size_t)y * (1024u * 1024u);
  const size_t i = ((size_t)blockIdx.x * 256 + threadIdx.x) * 8;
  *(short8*)(d + i) = cvt8(s + i);
}

// ---------------- 128x128 NT GEMM core (K=1024, BK=64) ----------------
// C[m][n] = sum_k A[m][k] * W[n][k]; 4 waves in 2x2, each 64x64 (4x4 frags).

DEVFN void gemm_core(const __hip_bfloat16* __restrict__ A,
                     const __hip_bfloat16* __restrict__ W,
                     __hip_bfloat16* As, __hip_bfloat16* Bs,
                     int mBase, int nBase, f32x4 (&acc)[4][4]) {
  const int t = threadIdx.x;
  const int lane = t & 63;
  const int w = t >> 6;
  const int wr = w >> 1, wc = w & 1;
  const int c = lane & 15, g = lane >> 4;
  const int srow = t >> 3, sslot = t & 7;

  for (int kt = 0; kt < 16; ++kt) {
    const int k0 = kt * 64;
    __syncthreads();  // previous iteration's frag reads done
#pragma unroll
    for (int i = 0; i < 4; ++i) {
      const int r = srow + 32 * i;
      gload_lds16(A + (size_t)(mBase + r) * 1024 + k0 + sslot * 8,
                  As + r * 64 + sslot * 8);
      gload_lds16(W + (size_t)(nBase + r) * 1024 + k0 + sslot * 8,
                  Bs + r * 64 + sslot * 8);
    }
    __syncthreads();  // vmcnt(0) drain before use

    short8 af[4][2], bfr[4][2];
#pragma unroll
    for (int m = 0; m < 4; ++m)
#pragma unroll
      for (int kk = 0; kk < 2; ++kk)
        af[m][kk] = *(const short8*)(As + (64 * wr + 16 * m + c) * 64 + kk * 32 + g * 8);
#pragma unroll
    for (int n = 0; n < 4; ++n)
#pragma unroll
      for (int kk = 0; kk < 2; ++kk)
        bfr[n][kk] = *(const short8*)(Bs + (64 * wc + 16 * n + c) * 64 + kk * 32 + g * 8);
#pragma unroll
    for (int kk = 0; kk < 2; ++kk)
#pragma unroll
      for (int m = 0; m < 4; ++m)
#pragma unroll
        for (int n = 0; n < 4; ++n)
          acc[m][n] = mfma16(af[m][kk], bfr[n][kk], acc[m][n]);
  }
}

// ---------------- QKV projection (z: 0=Q(scaled), 1=K, 2=V transposed) --------

__global__ __launch_bounds__(256, 3) void proj_qkv(
    const __hip_bfloat16* __restrict__ xq, const __hip_bfloat16* __restrict__ xk,
    const __hip_bfloat16* __restrict__ xv,
    const __hip_bfloat16* __restrict__ wq, const __hip_bfloat16* __restrict__ wk,
    const __hip_bfloat16* __restrict__ wv,
    const float* __restrict__ bq, const float* __restrict__ bk,
    const float* __restrict__ bv,
    __hip_bfloat16* __restrict__ qh, __hip_bfloat16* __restrict__ kh,
    __hip_bfloat16* __restrict__ vtr) {
  __shared__ __hip_bfloat16 As[128 * 64];
  __shared__ __hip_bfloat16 Bs[128 * 64];
  const int z = blockIdx.z;
  const __hip_bfloat16* A = (z == 0) ? xq : ((z == 1) ? xk : xv);
  const __hip_bfloat16* W = (z == 0) ? wq : ((z == 1) ? wk : wv);
  const float* bias = (z == 0) ? bq : ((z == 1) ? bk : bv);
  const int nBase = blockIdx.x * 128;
  const int mBase = blockIdx.y * 128;

  f32x4 acc[4][4] = {};
  gemm_core(A, W, As, Bs, mBase, nBase, acc);

  const int t = threadIdx.x;
  const int lane = t & 63;
  const int w = t >> 6;
  const int wr = w >> 1, wc = w & 1;
  const int c = lane & 15, g = lane >> 4;

  if (z < 2) {
    __hip_bfloat16* O = (z == 0) ? qh : kh;
    const float scale = (z == 0) ? 0.125f : 1.0f;  // 1/sqrt(Dh), exact in bf16
#pragma unroll
    for (int m = 0; m < 4; ++m) {
#pragma unroll
      for (int n = 0; n < 4; ++n) {
        const int row0 = mBase + 64 * wr + 16 * m + 4 * g;
        const int col = nBase + 64 * wc + 16 * n + c;
        const float bb = bias[col];
#pragma unroll
        for (int r = 0; r < 4; ++r)
          O[(size_t)(row0 + r) * 1024 + col] =
              __float2bfloat16((acc[m][n][r] + bb) * scale);
      }
    }
  } else {
    // V stored transposed per head: vtr[((b*16+h)*64+dh)*2048 + s]
#pragma unroll
    for (int m = 0; m < 4; ++m) {
#pragma unroll
      for (int n = 0; n < 4; ++n) {
        const int row0 = mBase + 64 * wr + 16 * m + 4 * g;  // global (b,s) row
        const int col = nBase + 64 * wc + 16 * n + c;       // d = h*64+dh
        const int bb = row0 >> 11;        // batch
        const int s0 = row0 & 2047;       // seq pos (4 consecutive)
        const float bv_ = bias[col];
        usv4 pk;
#pragma unroll
        for (int r = 0; r < 4; ++r) pk[r] = f2bf(acc[m][n][r] + bv_);
        *(usv4*)(vtr + ((size_t)(bb * 1024 + col)) * 2048 + s0) = pk;
      }
    }
  }
}

// ---------------- output projection (fp32 out + bias) ----------------

__global__ __launch_bounds__(256, 3) void out_proj(
    const __hip_bfloat16* __restrict__ ao, const __hip_bfloat16* __restrict__ wo,
    const float* __restrict__ bo, float* __restrict__ out) {
  __shared__ __hip_bfloat16 As[128 * 64];
  __shared__ __hip_bfloat16 Bs[128 * 64];
  const int nBase = blockIdx.x * 128;
  const int mBase = blockIdx.y * 128;

  f32x4 acc[4][4] = {};
  gemm_core(ao, wo, As, Bs, mBase, nBase, acc);

  const int t = threadIdx.x;
  const int lane = t & 63;
  const int w = t >> 6;
  const int wr = w >> 1, wc = w & 1;
  const int c = lane & 15, g = lane >> 4;
#pragma unroll
  for (int m = 0; m < 4; ++m) {
#pragma unroll
    for (int n = 0; n < 4; ++n) {
      const int row0 = mBase + 64 * wr + 16 * m + 4 * g;
      const int col = nBase + 64 * wc + 16 * n + c;
      const float bb = bo[col];
#pragma unroll
      for (int r = 0; r < 4; ++r)
        out[(size_t)(row0 + r) * 1024 + col] = acc[m][n][r] + bb;
    }
  }
}

// ---------------- flash attention ----------------
// grid (16 q-tiles, 32 bh). 4 waves; wave w owns q rows [32w, 32w+32).
// KV tile = 64. Q in registers (pre-scaled by 1/8 in projection).
// K: global_load_lds with XOR-swizzled source (read side applies same XOR).
// V^T, P: reg-staged into +8-padded LDS (conflict-free ds_read_b128).

__global__ __launch_bounds__(256, 2) void attn_fwd(
    const __hip_bfloat16* __restrict__ qh, const __hip_bfloat16* __restrict__ kh,
    const __hip_bfloat16* __restrict__ vtr, __hip_bfloat16* __restrict__ ao) {
  __shared__ __hip_bfloat16 Ks[64 * 64];    // [k_local][d], XOR-swizzled slots
  __shared__ __hip_bfloat16 Vs[64 * 72];    // [d][k_local], padded
  __shared__ __hip_bfloat16 Ps[128 * 72];   // [q_local][k_local], padded

  const int t = threadIdx.x;
  const int qt = blockIdx.x;
  const int bh = blockIdx.y;
  const int b = bh >> 4, h = bh & 15;
  const int lane = t & 63;
  const int w = t >> 6;
  const int c = lane & 15, g = lane >> 4;
  const size_t base = ((size_t)b * 2048) * 1024 + (size_t)h * 64;     // qh/kh/ao
  const size_t vbase = ((size_t)(b * 1024 + h * 64)) * 2048;          // vtr

  // Q fragments in registers: rows qt*128 + 32w + 16i + c, k = kk*32 + g*8
  short8 qf[2][2];
#pragma unroll
  for (int i = 0; i < 2; ++i)
#pragma unroll
    for (int kk = 0; kk < 2; ++kk)
      qf[i][kk] = *(const short8*)(qh + base +
          (size_t)(qt * 128 + 32 * w + 16 * i + c) * 1024 + kk * 32 + g * 8);

  float mrow[2][4], lrow[2][4];
  f32x4 accO[2][4] = {};
#pragma unroll
  for (int i = 0; i < 2; ++i)
#pragma unroll
    for (int r = 0; r < 4; ++r) { mrow[i][r] = -1e30f; lrow[i][r] = 0.f; }

  const f32x4 kZero = {0.f, 0.f, 0.f, 0.f};
  const int srow = t >> 3, sslot = t & 7;

  for (int kv = 0; kv < 32; ++kv) {
    const int kbase = kv * 64;
    __syncthreads();  // previous tile's LDS reads complete
    // K tile: swizzled source slot, linear LDS dest (lane-contiguous)
#pragma unroll
    for (int i2 = 0; i2 < 2; ++i2) {
      const int r = srow + 32 * i2;
      const int ss = sslot ^ (r & 7);
      gload_lds16(kh + base + (size_t)(kbase + r) * 1024 + ss * 8,
                  Ks + r * 64 + sslot * 8);
    }
    // V^T tile: reg-staged into padded LDS
    short8 vtmp[2];
#pragma unroll
    for (int i2 = 0; i2 < 2; ++i2) {
      const int d = srow + 32 * i2;
      vtmp[i2] = *(const short8*)(vtr + vbase + (size_t)d * 2048 + kbase + sslot * 8);
    }
#pragma unroll
    for (int i2 = 0; i2 < 2; ++i2) {
      const int d = srow + 32 * i2;
      *(short8*)(Vs + d * 72 + sslot * 8) = vtmp[i2];
    }
    __syncthreads();

    // S = Q K^T (scores; scale folded into Q)
    f32x4 accS[2][4];
#pragma unroll
    for (int kj = 0; kj < 4; ++kj) {
      const int rw = 16 * kj + c;  // K row (score col); rw&7 == c&7
      short8 kf0 = *(const short8*)(Ks + rw * 64 + ((0 + g) ^ (c & 7)) * 8);
      short8 kf1 = *(const short8*)(Ks + rw * 64 + ((4 + g) ^ (c & 7)) * 8);
#pragma unroll
      for (int i = 0; i < 2; ++i) {
        accS[i][kj] = mfma16(qf[i][0], kf0, kZero);
        accS[i][kj] = mfma16(qf[i][1], kf1, accS[i][kj]);
      }
    }

    // online softmax: D-layout rows are lane-group-local; col-reduce via shfl
#pragma unroll
    for (int i = 0; i < 2; ++i) {
      float corr[4];
#pragma unroll
      for (int r = 0; r < 4; ++r) {
        float v = accS[i][0][r];
#pragma unroll
        for (int kj = 1; kj < 4; ++kj) v = fmaxf(v, accS[i][kj][r]);
#pragma unroll
        for (int msk = 1; msk <= 8; msk <<= 1)
          v = fmaxf(v, __shfl_xor(v, msk, 64));
        const float mn = fmaxf(mrow[i][r], v);
        corr[r] = exp2f((mrow[i][r] - mn) * LOG2E);
        mrow[i][r] = mn;
      }
      float rsum[4] = {0.f, 0.f, 0.f, 0.f};
#pragma unroll
      for (int kj = 0; kj < 4; ++kj)
#pragma unroll
        for (int r = 0; r < 4; ++r) {
          const float p = exp2f((accS[i][kj][r] - mrow[i][r]) * LOG2E);
          accS[i][kj][r] = p;
          rsum[r] += p;
        }
#pragma unroll
      for (int r = 0; r < 4; ++r) {
        float s = rsum[r];
#pragma unroll
        for (int msk = 1; msk <= 8; msk <<= 1) s += __shfl_xor(s, msk, 64);
        lrow[i][r] = lrow[i][r] * corr[r] + s;
#pragma unroll
        for (int j = 0; j < 4; ++j) accO[i][j][r] *= corr[r];
      }
      // P strip to padded LDS (wave-private rows; in-order DS pipe, no barrier)
#pragma unroll
      for (int kj = 0; kj < 4; ++kj)
#pragma unroll
        for (int r = 0; r < 4; ++r)
          Ps[(32 * w + 16 * i + 4 * g + r) * 72 + 16 * kj + c] =
              __float2bfloat16(accS[i][kj][r]);
    }

    // O += P V   (NT form: A = P rows q, B = V^T rows d, contract k)
#pragma unroll
    for (int kk2 = 0; kk2 < 2; ++kk2) {
      short8 pa[2], vb[4];
#pragma unroll
      for (int i = 0; i < 2; ++i)
        pa[i] = *(const short8*)(Ps + (32 * w + 16 * i + c) * 72 + kk2 * 32 + g * 8);
#pragma unroll
      for (int j = 0; j < 4; ++j)
        vb[j] = *(const short8*)(Vs + (16 * j + c) * 72 + kk2 * 32 + g * 8);
#pragma unroll
      for (int i = 0; i < 2; ++i)
#pragma unroll
        for (int j = 0; j < 4; ++j)
          accO[i][j] = mfma16(pa[i], vb[j], accO[i][j]);
    }
  }

  // normalize by row sums, store bf16 [b][s][h*64+d]
#pragma unroll
  for (int i = 0; i < 2; ++i) {
    float rl[4];
#pragma unroll
    for (int r = 0; r < 4; ++r) rl[r] = 1.0f / lrow[i][r];
#pragma unroll
    for (int j = 0; j < 4; ++j)
#pragma unroll
      for (int r = 0; r < 4; ++r) {
        const int qrow = qt * 128 + 32 * w + 16 * i + 4 * g + r;
        ao[base + (size_t)qrow * 1024 + 16 * j + c] =
            __float2bfloat16(accO[i][j][r] * rl[r]);
      }
  }
}

// ---------------- launch ----------------

extern "C" void kernel_launch(void* const* d_in, const int* in_sizes, int n_in,
                              void* d_out, int out_size, void* d_ws, size_t ws_size,
                              hipStream_t stream) {
  (void)in_sizes; (void)n_in; (void)out_size; (void)ws_size;
  const float* query = (const float*)d_in[0];
  const float* key_  = (const float*)d_in[1];
  const float* value = (const float*)d_in[2];
  const float* Wq = (const float*)d_in[3];
  const float* bq = (const float*)d_in[4];
  const float* Wk = (const float*)d_in[5];
  const float* bk = (const float*)d_in[6];
  const float* Wv = (const float*)d_in[7];
  const float* bv = (const float*)d_in[8];
  const float* Wo = (const float*)d_in[9];
  const float* bo = (const float*)d_in[10];

  const size_t NX = (size_t)4096 * 1024;   // per converted input / activation
  const size_t NW = (size_t)1024 * 1024;   // per converted weight
  __hip_bfloat16* ws  = (__hip_bfloat16*)d_ws;
  __hip_bfloat16* xq  = ws;                // xq,xk,xv contiguous (3*NX)
  __hip_bfloat16* wqb = ws + 3 * NX;       // wq,wk,wv,wo contiguous (4*NW)
  __hip_bfloat16* qh  = wqb + 4 * NW;
  __hip_bfloat16* kh  = qh + NX;
  __hip_bfloat16* vtr = kh + NX;           // [b][h][dh][s]
  __hip_bfloat16* ao  = vtr + NX;          // [b][s][h*64+dh]
  // total ws use: 64 MiB

  cvt_inputs<<<dim3(2048, 3), 256, 0, stream>>>(query, key_, value, xq);
  cvt_weights<<<dim3(512, 4), 256, 0, stream>>>(Wq, Wk, Wv, Wo, wqb);
  proj_qkv<<<dim3(8, 32, 3), 256, 0, stream>>>(
      xq, xq + NX, xq + 2 * NX, wqb, wqb + NW, wqb + 2 * NW,
      bq, bk, bv, qh, kh, vtr);
  attn_fwd<<<dim3(16, 32), 256, 0, stream>>>(qh, kh, vtr, ao);
  out_proj<<<dim3(8, 32), 256, 0, stream>>>(ao, wqb + 3 * NW, bo, (float*)d_out);
}

// Round 2
// 266.658 us; speedup vs baseline: 1.1995x; 1.1995x over previous
//
#include <hip/hip_runtime.h>
#include <hip/hip_bf16.h>
#include <stdint.h>
#include <stddef.h>

// MHA forward, B=2 S=2048 D=1024 H=16 Dh=64, bf16 MFMA pipeline.
// cvt(fp32->bf16) -> proj QKV (2-phase dbuf NT GEMM; V stored transposed per
// head; Q pre-scaled by log2e/sqrt(Dh)) -> flash attention with kv-split x2
// (swapped QK^T, in-register softmax/P, counted-vmcnt K/V pipeline)
// -> merge partials -> output proj (fp32 out).

typedef __attribute__((ext_vector_type(8))) short short8;   // 8 x bf16
typedef __attribute__((ext_vector_type(4))) float f32x4;    // MFMA C/D
typedef __attribute__((ext_vector_type(4))) unsigned short usv4;

#define DEVFN static __device__ __forceinline__

constexpr float LOG2E = 1.44269504088896340736f;
constexpr size_t NXC = 4194304;   // 4096*1024 elements

DEVFN f32x4 mfma16(short8 a, short8 b, f32x4 c) {
  return __builtin_amdgcn_mfma_f32_16x16x32_bf16(a, b, c, 0, 0, 0);
}

// async global->LDS, 16B per lane. Dest must be linear in lane id.
DEVFN void gload_lds16(const void* g, void* l) {
  __builtin_amdgcn_global_load_lds(
      (const __attribute__((address_space(1))) unsigned int*)g,
      (__attribute__((address_space(3))) unsigned int*)l, 16, 0, 0);
}

DEVFN unsigned short f2bf(float x) {
  union { __hip_bfloat16 h; unsigned short u; } cv;
  cv.h = __float2bfloat16(x);
  return cv.u;
}

DEVFN float bf2f(unsigned short u) {
  union { unsigned int i; float f; } cv;
  cv.i = ((unsigned int)u) << 16;
  return cv.f;
}

DEVFN short8 cvt8(const float* s) {
  float4 a = *(const float4*)(s);
  float4 b = *(const float4*)(s + 4);
  short8 o;
  o[0] = (short)f2bf(a.x); o[1] = (short)f2bf(a.y);
  o[2] = (short)f2bf(a.z); o[3] = (short)f2bf(a.w);
  o[4] = (short)f2bf(b.x); o[5] = (short)f2bf(b.y);
  o[6] = (short)f2bf(b.z); o[7] = (short)f2bf(b.w);
  return o;
}

// ---------------- fp32 -> bf16 conversion ----------------

__global__ __launch_bounds__(256) void cvt_inputs(
    const float* __restrict__ s0, const float* __restrict__ s1,
    const float* __restrict__ s2, __hip_bfloat16* __restrict__ dst) {
  const int y = blockIdx.y;
  const float* s = (y == 0) ? s0 : ((y == 1) ? s1 : s2);
  __hip_bfloat16* d = dst + (size_t)y * NXC;
  const size_t i = ((size_t)blockIdx.x * 256 + threadIdx.x) * 8;
  *(short8*)(d + i) = cvt8(s + i);
}

__global__ __launch_bounds__(256) void cvt_weights(
    const float* __restrict__ s0, const float* __restrict__ s1,
    const float* __restrict__ s2, const float* __restrict__ s3,
    __hip_bfloat16* __restrict__ dst) {
  const int y = blockIdx.y;
  const float* s = (y == 0) ? s0 : (y == 1) ? s1 : (y == 2) ? s2 : s3;
  __hip_bfloat16* d = dst + (size_t)y * (1024u * 1024u);
  const size_t i = ((size_t)blockIdx.x * 256 + threadIdx.x) * 8;
  *(short8*)(d + i) = cvt8(s + i);
}

// ------- 128x128 NT GEMM core (K=1024, BK=32, dbuf + counted vmcnt) -------
// C[m][n] = sum_k A[m][k] * W[n][k]; 4 waves in 2x2, each 64x64 (4x4 frags).
// As/Bs are [2][128*32] element buffers.

DEVFN void gemm_core(const __hip_bfloat16* __restrict__ A,
                     const __hip_bfloat16* __restrict__ W,
                     __hip_bfloat16* As, __hip_bfloat16* Bs,
                     int mBase, int nBase, f32x4 (&acc)[4][4]) {
  const int t = threadIdx.x;
  const int lane = t & 63;
  const int w = t >> 6;
  const int wr = w >> 1, wc = w & 1;
  const int c = lane & 15, g = lane >> 4;
  const int srow = t >> 2, sslot = t & 3;

  auto STAGE = [&](int kt, int bufsel) {
    const int k0 = kt * 32;
#pragma unroll
    for (int inst = 0; inst < 2; ++inst) {
      const int row = 64 * inst + srow;
      gload_lds16(A + (size_t)(mBase + row) * 1024 + k0 + sslot * 8,
                  As + bufsel * 4096 + row * 32 + sslot * 8);
      gload_lds16(W + (size_t)(nBase + row) * 1024 + k0 + sslot * 8,
                  Bs + bufsel * 4096 + row * 32 + sslot * 8);
    }
  };

  STAGE(0, 0);
  for (int kt = 0; kt < 32; ++kt) {
    const int cur = kt & 1;
    if (kt < 31) {
      STAGE(kt + 1, cur ^ 1);
      asm volatile("s_waitcnt vmcnt(4)" ::: "memory");
    } else {
      asm volatile("s_waitcnt vmcnt(0)" ::: "memory");
    }
    __builtin_amdgcn_s_barrier();
    asm volatile("" ::: "memory");

    short8 af[4], bfr[4];
#pragma unroll
    for (int m = 0; m < 4; ++m)
      af[m] = *(const short8*)(As + cur * 4096 + (64 * wr + 16 * m + c) * 32 + g * 8);
#pragma unroll
    for (int n = 0; n < 4; ++n)
      bfr[n] = *(const short8*)(Bs + cur * 4096 + (64 * wc + 16 * n + c) * 32 + g * 8);
#pragma unroll
    for (int m = 0; m < 4; ++m)
#pragma unroll
      for (int n = 0; n < 4; ++n)
        acc[m][n] = mfma16(af[m], bfr[n], acc[m][n]);

    asm volatile("s_waitcnt lgkmcnt(0)" ::: "memory");
    __builtin_amdgcn_s_barrier();
  }
}

// ---------------- QKV projection (z: 0=Q(scaled), 1=K, 2=V transposed) -----

__global__ __launch_bounds__(256, 3) void proj_qkv(
    const __hip_bfloat16* __restrict__ xq, const __hip_bfloat16* __restrict__ xk,
    const __hip_bfloat16* __restrict__ xv,
    const __hip_bfloat16* __restrict__ wq, const __hip_bfloat16* __restrict__ wk,
    const __hip_bfloat16* __restrict__ wv,
    const float* __restrict__ bq, const float* __restrict__ bk,
    const float* __restrict__ bv,
    __hip_bfloat16* __restrict__ qh, __hip_bfloat16* __restrict__ kh,
    __hip_bfloat16* __restrict__ vtr) {
  __shared__ __hip_bfloat16 As[2 * 128 * 32];
  __shared__ __hip_bfloat16 Bs[2 * 128 * 32];
  const int z = blockIdx.z;
  const __hip_bfloat16* A = (z == 0) ? xq : ((z == 1) ? xk : xv);
  const __hip_bfloat16* W = (z == 0) ? wq : ((z == 1) ? wk : wv);
  const float* bias = (z == 0) ? bq : ((z == 1) ? bk : bv);
  const int nBase = blockIdx.x * 128;
  const int mBase = blockIdx.y * 128;

  f32x4 acc[4][4] = {};
  gemm_core(A, W, As, Bs, mBase, nBase, acc);

  const int t = threadIdx.x;
  const int lane = t & 63;
  const int w = t >> 6;
  const int wr = w >> 1, wc = w & 1;
  const int c = lane & 15, g = lane >> 4;

  if (z < 2) {
    __hip_bfloat16* O = (z == 0) ? qh : kh;
    // Q: 1/sqrt(Dh) * log2(e), so softmax is pure exp2
    const float scale = (z == 0) ? (0.125f * LOG2E) : 1.0f;
#pragma unroll
    for (int m = 0; m < 4; ++m) {
#pragma unroll
      for (int n = 0; n < 4; ++n) {
        const int row0 = mBase + 64 * wr + 16 * m + 4 * g;
        const int col = nBase + 64 * wc + 16 * n + c;
        const float bb = bias[col];
#pragma unroll
        for (int r = 0; r < 4; ++r)
          O[(size_t)(row0 + r) * 1024 + col] =
              __float2bfloat16((acc[m][n][r] + bb) * scale);
      }
    }
  } else {
    // V stored transposed per head: vtr[((b*16+h)*64+dh)*2048 + s]
#pragma unroll
    for (int m = 0; m < 4; ++m) {
#pragma unroll
      for (int n = 0; n < 4; ++n) {
        const int row0 = mBase + 64 * wr + 16 * m + 4 * g;  // global (b,s) row
        const int col = nBase + 64 * wc + 16 * n + c;       // d = h*64+dh
        const int bb = row0 >> 11;        // batch
        const int s0 = row0 & 2047;       // seq pos (4 consecutive)
        const float bv_ = bias[col];
        usv4 pk;
#pragma unroll
        for (int r = 0; r < 4; ++r) pk[r] = f2bf(acc[m][n][r] + bv_);
        *(usv4*)(vtr + ((size_t)(bb * 1024 + col)) * 2048 + s0) = pk;
      }
    }
  }
}

// ---------------- output projection (fp32 out + bias) ----------------

__global__ __launch_bounds__(256, 3) void out_proj(
    const __hip_bfloat16* __restrict__ ao, const __hip_bfloat16* __restrict__ wo,
    const float* __restrict__ bo, float* __restrict__ out) {
  __shared__ __hip_bfloat16 As[2 * 128 * 32];
  __shared__ __hip_bfloat16 Bs[2 * 128 * 32];
  const int nBase = blockIdx.x * 128;
  const int mBase = blockIdx.y * 128;

  f32x4 acc[4][4] = {};
  gemm_core(ao, wo, As, Bs, mBase, nBase, acc);

  const int t = threadIdx.x;
  const int lane = t & 63;
  const int w = t >> 6;
  const int wr = w >> 1, wc = w & 1;
  const int c = lane & 15, g = lane >> 4;
#pragma unroll
  for (int m = 0; m < 4; ++m) {
#pragma unroll
    for (int n = 0; n < 4; ++n) {
      const int row0 = mBase + 64 * wr + 16 * m + 4 * g;
      const int col = nBase + 64 * wc + 16 * n + c;
      const float bb = bo[col];
#pragma unroll
      for (int r = 0; r < 4; ++r)
        out[(size_t)(row0 + r) * 1024 + col] = acc[m][n][r] + bb;
    }
  }
}

// ---------------- flash attention, kv-split x2, partial outputs -----------
// grid: 1024 flat = (16 qtiles, 32 bh, 2 kv-halves), XCD-swizzled so each
// XCD owns 4 bh (K/V 2MB fits its L2). 4 waves; wave w owns q rows
// [qt*128+32w, +32). KV tile 64, 16 tiles per half, dbuf + vmcnt(4).
// Swapped QK^T: mfma(K,Q) puts a full P row per lane (q = 16i + (lane&15)),
// softmax fully in-register; P redistributed to PV A-frags via shfl.

__global__ __launch_bounds__(256, 3) void attn_partial(
    const __hip_bfloat16* __restrict__ qh, const __hip_bfloat16* __restrict__ kh,
    const __hip_bfloat16* __restrict__ vtr, __hip_bfloat16* __restrict__ po,
    float* __restrict__ Mbuf, float* __restrict__ Lbuf) {
  __shared__ __hip_bfloat16 Ks[2][64 * 64];
  __shared__ __hip_bfloat16 Vs[2][64 * 64];

  const int t = threadIdx.x;
  const int fid = blockIdx.x;
  const int xcd = fid & 7, idx = fid >> 3;
  const int bh = xcd * 4 + (idx & 3);
  const int qt = (idx >> 2) & 15;
  const int half = idx >> 6;
  const int b = bh >> 4, h = bh & 15;
  const int lane = t & 63;
  const int w = t >> 6;
  const int c = lane & 15, g = lane >> 4;
  const int c7 = c & 7;
  const size_t base = ((size_t)b * 2048) * 1024 + (size_t)h * 64;   // qh/kh/po
  const size_t vbase = ((size_t)(b * 1024 + h * 64)) * 2048;        // vtr
  const int halfBase = half * 1024;

  // Q B-fragments: rows qt*128+32w+16i+c, d-cols kk*32+g*8 (pre-scaled)
  short8 qf[2][2];
#pragma unroll
  for (int i = 0; i < 2; ++i)
#pragma unroll
    for (int kk = 0; kk < 2; ++kk)
      qf[i][kk] = *(const short8*)(qh + base +
          (size_t)(qt * 128 + 32 * w + 16 * i + c) * 1024 + kk * 32 + g * 8);

  f32x4 accO[2][4] = {};
  float mreg[2] = {-1e30f, -1e30f};
  float lreg[2] = {0.f, 0.f};

  const int srow = t >> 3, sslot = t & 7;

  auto STAGE = [&](int tile, int bufsel) {
    const int kbase = halfBase + tile * 64;
#pragma unroll
    for (int ii = 0; ii < 2; ++ii) {
      const int row = srow + 32 * ii;
      const int ss = sslot ^ (row & 7);   // source-side swizzle (involution)
      gload_lds16(kh + base + (size_t)(kbase + row) * 1024 + ss * 8,
                  &Ks[bufsel][row * 64 + sslot * 8]);
      gload_lds16(vtr + vbase + (size_t)row * 2048 + kbase + ss * 8,
                  &Vs[bufsel][row * 64 + sslot * 8]);
    }
  };

  STAGE(0, 0);

  for (int tt = 0; tt < 16; ++tt) {
    const int cur = tt & 1;
    if (tt < 15) {
      STAGE(tt + 1, cur ^ 1);
      asm volatile("s_waitcnt vmcnt(4)" ::: "memory");
    } else {
      asm volatile("s_waitcnt vmcnt(0)" ::: "memory");
    }
    __builtin_amdgcn_s_barrier();
    asm volatile("" ::: "memory");

    // QK^T swapped: A=K rows (k), B=Q rows (q) -> lane holds S[k=16kj+4g+r][q=16i+c]
    f32x4 accS[2][4];
#pragma unroll
    for (int kj = 0; kj < 4; ++kj) {
      const __hip_bfloat16* kr = &Ks[cur][(16 * kj + c) * 64];
      short8 kf0 = *(const short8*)(kr + ((0 + g) ^ c7) * 8);
      short8 kf1 = *(const short8*)(kr + ((4 + g) ^ c7) * 8);
#pragma unroll
      for (int i = 0; i < 2; ++i) {
        f32x4 z = {0.f, 0.f, 0.f, 0.f};
        z = mfma16(kf0, qf[i][0], z);
        accS[i][kj] = mfma16(kf1, qf[i][1], z);
      }
    }

    // online softmax, fully in-register (scores already in log2 units)
    unsigned int pp[2][4][2];
#pragma unroll
    for (int i = 0; i < 2; ++i) {
      float pmax = accS[i][0][0];
#pragma unroll
      for (int kj = 0; kj < 4; ++kj)
#pragma unroll
        for (int r = 0; r < 4; ++r) pmax = fmaxf(pmax, accS[i][kj][r]);
      pmax = fmaxf(pmax, __shfl_xor(pmax, 16, 64));
      pmax = fmaxf(pmax, __shfl_xor(pmax, 32, 64));
      const float mn = fmaxf(mreg[i], pmax);
      const float corr = exp2f(mreg[i] - mn);
      mreg[i] = mn;
      float rsum = 0.f;
#pragma unroll
      for (int kj = 0; kj < 4; ++kj) {
        const float p0 = exp2f(accS[i][kj][0] - mn);
        const float p1 = exp2f(accS[i][kj][1] - mn);
        const float p2 = exp2f(accS[i][kj][2] - mn);
        const float p3 = exp2f(accS[i][kj][3] - mn);
        rsum += (p0 + p1) + (p2 + p3);
        pp[i][kj][0] = (unsigned)f2bf(p0) | ((unsigned)f2bf(p1) << 16);
        pp[i][kj][1] = (unsigned)f2bf(p2) | ((unsigned)f2bf(p3) << 16);
      }
      rsum += __shfl_xor(rsum, 16, 64);
      rsum += __shfl_xor(rsum, 32, 64);
      lreg[i] = lreg[i] * corr + rsum;
      // rescale accO rows (row q = 16i+4g+r; corr lives at lane c=4g+r)
#pragma unroll
      for (int r = 0; r < 4; ++r) {
        const float cd = __shfl(corr, 20 * g + r, 64);
#pragma unroll
        for (int jj = 0; jj < 4; ++jj) accO[i][jj][r] *= cd;
      }
    }

    // PV: build P A-frags via shfl redistribution, B=V^T rows (dh)
#pragma unroll
    for (int kk2 = 0; kk2 < 2; ++kk2) {
      short8 pa[2];
      const int src0 = c + 32 * (g & 1);
      const int src1 = src0 + 16;
      const bool gh = (g >> 1) != 0;
#pragma unroll
      for (int i = 0; i < 2; ++i) {
        const unsigned a0 = (unsigned)__shfl((int)pp[i][2 * kk2][0], src0, 64);
        const unsigned a1 = (unsigned)__shfl((int)pp[i][2 * kk2][1], src0, 64);
        const unsigned a2 = (unsigned)__shfl((int)pp[i][2 * kk2][0], src1, 64);
        const unsigned a3 = (unsigned)__shfl((int)pp[i][2 * kk2][1], src1, 64);
        const unsigned b0 = (unsigned)__shfl((int)pp[i][2 * kk2 + 1][0], src0, 64);
        const unsigned b1 = (unsigned)__shfl((int)pp[i][2 * kk2 + 1][1], src0, 64);
        const unsigned b2 = (unsigned)__shfl((int)pp[i][2 * kk2 + 1][0], src1, 64);
        const unsigned b3 = (unsigned)__shfl((int)pp[i][2 * kk2 + 1][1], src1, 64);
        union { unsigned u[4]; short8 v; } uu;
        uu.u[0] = gh ? b0 : a0;
        uu.u[1] = gh ? b1 : a1;
        uu.u[2] = gh ? b2 : a2;
        uu.u[3] = gh ? b3 : a3;
        pa[i] = uu.v;
      }
#pragma unroll
      for (int jj = 0; jj < 4; ++jj) {
        const short8 vb = *(const short8*)(
            &Vs[cur][(16 * jj + c) * 64 + ((4 * kk2 + g) ^ c7) * 8]);
        accO[0][jj] = mfma16(pa[0], vb, accO[0][jj]);
        accO[1][jj] = mfma16(pa[1], vb, accO[1][jj]);
      }
    }

    asm volatile("s_waitcnt lgkmcnt(0)" ::: "memory");
    __builtin_amdgcn_s_barrier();
  }

  // epilogue: normalized partial O (bf16) + per-row m,l
#pragma unroll
  for (int i = 0; i < 2; ++i) {
    const float linv = 1.0f / lreg[i];
#pragma unroll
    for (int r = 0; r < 4; ++r) {
      const float ld = __shfl(linv, 20 * g + r, 64);
      const int qrow = qt * 128 + 32 * w + 16 * i + 4 * g + r;
#pragma unroll
      for (int jj = 0; jj < 4; ++jj)
        po[(size_t)half * NXC + base + (size_t)qrow * 1024 + 16 * jj + c] =
            __float2bfloat16(accO[i][jj][r] * ld);
    }
  }
  if (lane < 16) {
#pragma unroll
    for (int i = 0; i < 2; ++i) {
      const int qrow = qt * 128 + 32 * w + 16 * i + c;
      const int off = half * 65536 + bh * 2048 + qrow;
      Mbuf[off] = mreg[i];
      Lbuf[off] = lreg[i];
    }
  }
}

// ---------------- merge the two kv-half partials ----------------

__global__ __launch_bounds__(256) void attn_merge(
    const __hip_bfloat16* __restrict__ po, const float* __restrict__ Mbuf,
    const float* __restrict__ Lbuf, __hip_bfloat16* __restrict__ ao) {
  const size_t e = ((size_t)blockIdx.x * 256 + threadIdx.x) * 8;
  const int srow = (int)(e >> 10);
  const int d0 = (int)(e & 1023);
  const int b = srow >> 11, s = srow & 2047;
  const int h = d0 >> 6;
  const int idx = (b * 16 + h) * 2048 + s;
  const float m0 = Mbuf[idx], m1 = Mbuf[65536 + idx];
  const float l0 = Lbuf[idx], l1 = Lbuf[65536 + idx];
  const float Mx = fmaxf(m0, m1);
  float w0 = exp2f(m0 - Mx) * l0;
  float w1 = exp2f(m1 - Mx) * l1;
  const float inv = 1.0f / (w0 + w1);
  w0 *= inv; w1 *= inv;
  const short8 x0 = *(const short8*)(po + e);
  const short8 x1 = *(const short8*)(po + NXC + e);
  short8 o;
#pragma unroll
  for (int j = 0; j < 8; ++j) {
    const float v = w0 * bf2f((unsigned short)x0[j]) +
                    w1 * bf2f((unsigned short)x1[j]);
    o[j] = (short)f2bf(v);
  }
  *(short8*)(ao + e) = o;
}

// ---------------- launch ----------------

extern "C" void kernel_launch(void* const* d_in, const int* in_sizes, int n_in,
                              void* d_out, int out_size, void* d_ws, size_t ws_size,
                              hipStream_t stream) {
  (void)in_sizes; (void)n_in; (void)out_size; (void)ws_size;
  const float* query = (const float*)d_in[0];
  const float* key_  = (const float*)d_in[1];
  const float* value = (const float*)d_in[2];
  const float* Wq = (const float*)d_in[3];
  const float* bq = (const float*)d_in[4];
  const float* Wk = (const float*)d_in[5];
  const float* bk = (const float*)d_in[6];
  const float* Wv = (const float*)d_in[7];
  const float* bv = (const float*)d_in[8];
  const float* Wo = (const float*)d_in[9];
  const float* bo = (const float*)d_in[10];

  const size_t NX = NXC;                   // per converted input / activation
  const size_t NW = (size_t)1024 * 1024;   // per converted weight
  __hip_bfloat16* ws  = (__hip_bfloat16*)d_ws;
  __hip_bfloat16* xq  = ws;                // xq,xk,xv contiguous (3*NX)
  __hip_bfloat16* wqb = ws + 3 * NX;       // wq,wk,wv,wo contiguous (4*NW)
  __hip_bfloat16* qh  = wqb + 4 * NW;
  __hip_bfloat16* kh  = qh + NX;
  __hip_bfloat16* vtr = kh + NX;           // [b][h][dh][s]
  __hip_bfloat16* ao  = vtr + NX;          // [b][s][h*64+dh]
  // after proj_qkv, xq/xk/xv are dead: reuse for attention partials
  __hip_bfloat16* po = ws;                 // [2][b][s][h*64+dh] (2*NX el)
  float* Mf = (float*)(ws + 2 * NX);       // [2][32][2048]
  float* Lf = Mf + 131072;
  // total ws use: 64 MiB

  cvt_inputs<<<dim3(2048, 3), 256, 0, stream>>>(query, key_, value, xq);
  cvt_weights<<<dim3(512, 4), 256, 0, stream>>>(Wq, Wk, Wv, Wo, wqb);
  proj_qkv<<<dim3(8, 32, 3), 256, 0, stream>>>(
      xq, xq + NX, xq + 2 * NX, wqb, wqb + NW, wqb + 2 * NW,
      bq, bk, bv, qh, kh, vtr);
  attn_partial<<<dim3(1024), 256, 0, stream>>>(qh, kh, vtr, po, Mf, Lf);
  attn_merge<<<dim3(2048), 256, 0, stream>>>(po, Mf, Lf, ao);
  out_proj<<<dim3(8, 32), 256, 0, stream>>>(ao, wqb + 3 * NW, bo, (float*)d_out);
}

// Round 3
// 248.597 us; speedup vs baseline: 1.2867x; 1.0727x over previous
//
#include <hip/hip_runtime.h>
#include <hip/hip_bf16.h>
#include <stdint.h>
#include <stddef.h>

// MHA forward, B=2 S=2048 D=1024 H=16 Dh=64, bf16 MFMA pipeline.
// cvt(fp32->bf16) -> proj QKV (2-phase dbuf NT GEMM; V stored transposed per
// head; Q pre-scaled by log2e/sqrt(Dh)) -> flash attention with kv-split x2
// (32x32 MFMA, swapped QK^T AND swapped PV so q is lane-local; in-register
// softmax; P via cvt_pk_bf16 + permlane32_swap; defer-max; setprio)
// -> merge partials -> output proj (fp32 out).

typedef __attribute__((ext_vector_type(8))) short short8;   // 8 x bf16
typedef __attribute__((ext_vector_type(4))) float f32x4;    // 16x16 MFMA C/D
typedef __attribute__((ext_vector_type(16))) float f32x16;  // 32x32 MFMA C/D
typedef __attribute__((ext_vector_type(4))) unsigned short usv4;

#define DEVFN static __device__ __forceinline__

constexpr float LOG2E = 1.44269504088896340736f;
constexpr size_t NXC = 4194304;   // 4096*1024 elements

DEVFN f32x4 mfma16(short8 a, short8 b, f32x4 c) {
  return __builtin_amdgcn_mfma_f32_16x16x32_bf16(a, b, c, 0, 0, 0);
}

DEVFN f32x16 mfma32(short8 a, short8 b, f32x16 c) {
  return __builtin_amdgcn_mfma_f32_32x32x16_bf16(a, b, c, 0, 0, 0);
}

// async global->LDS, 16B per lane. Dest must be linear in lane id.
DEVFN void gload_lds16(const void* g, void* l) {
  __builtin_amdgcn_global_load_lds(
      (const __attribute__((address_space(1))) unsigned int*)g,
      (__attribute__((address_space(3))) unsigned int*)l, 16, 0, 0);
}

DEVFN unsigned short f2bf(float x) {
  union { __hip_bfloat16 h; unsigned short u; } cv;
  cv.h = __float2bfloat16(x);
  return cv.u;
}

DEVFN float bf2f(unsigned short u) {
  union { unsigned int i; float f; } cv;
  cv.i = ((unsigned int)u) << 16;
  return cv.f;
}

DEVFN unsigned cvt_pk(float lo, float hi) {   // u32 = {bf16(lo), bf16(hi)<<16}
  unsigned r;
  asm("v_cvt_pk_bf16_f32 %0, %1, %2" : "=v"(r) : "v"(lo), "v"(hi));
  return r;
}

DEVFN short8 cvt8(const float* s) {
  float4 a = *(const float4*)(s);
  float4 b = *(const float4*)(s + 4);
  short8 o;
  o[0] = (short)f2bf(a.x); o[1] = (short)f2bf(a.y);
  o[2] = (short)f2bf(a.z); o[3] = (short)f2bf(a.w);
  o[4] = (short)f2bf(b.x); o[5] = (short)f2bf(b.y);
  o[6] = (short)f2bf(b.z); o[7] = (short)f2bf(b.w);
  return o;
}

// ---------------- fp32 -> bf16 conversion ----------------

__global__ __launch_bounds__(256) void cvt_inputs(
    const float* __restrict__ s0, const float* __restrict__ s1,
    const float* __restrict__ s2, __hip_bfloat16* __restrict__ dst) {
  const int y = blockIdx.y;
  const float* s = (y == 0) ? s0 : ((y == 1) ? s1 : s2);
  __hip_bfloat16* d = dst + (size_t)y * NXC;
  const size_t i = ((size_t)blockIdx.x * 256 + threadIdx.x) * 8;
  *(short8*)(d + i) = cvt8(s + i);
}

__global__ __launch_bounds__(256) void cvt_weights(
    const float* __restrict__ s0, const float* __restrict__ s1,
    const float* __restrict__ s2, const float* __restrict__ s3,
    __hip_bfloat16* __restrict__ dst) {
  const int y = blockIdx.y;
  const float* s = (y == 0) ? s0 : (y == 1) ? s1 : (y == 2) ? s2 : s3;
  __hip_bfloat16* d = dst + (size_t)y * (1024u * 1024u);
  const size_t i = ((size_t)blockIdx.x * 256 + threadIdx.x) * 8;
  *(short8*)(d + i) = cvt8(s + i);
}

// ------- 128x128 NT GEMM core (K=1024, BK=32, dbuf + counted vmcnt) -------
// C[m][n] = sum_k A[m][k] * W[n][k]; 4 waves in 2x2, each 64x64 (4x4 frags).

DEVFN void gemm_core(const __hip_bfloat16* __restrict__ A,
                     const __hip_bfloat16* __restrict__ W,
                     __hip_bfloat16* As, __hip_bfloat16* Bs,
                     int mBase, int nBase, f32x4 (&acc)[4][4]) {
  const int t = threadIdx.x;
  const int lane = t & 63;
  const int w = t >> 6;
  const int wr = w >> 1, wc = w & 1;
  const int c = lane & 15, g = lane >> 4;
  const int srow = t >> 2, sslot = t & 3;

  auto STAGE = [&](int kt, int bufsel) {
    const int k0 = kt * 32;
#pragma unroll
    for (int inst = 0; inst < 2; ++inst) {
      const int row = 64 * inst + srow;
      gload_lds16(A + (size_t)(mBase + row) * 1024 + k0 + sslot * 8,
                  As + bufsel * 4096 + row * 32 + sslot * 8);
      gload_lds16(W + (size_t)(nBase + row) * 1024 + k0 + sslot * 8,
                  Bs + bufsel * 4096 + row * 32 + sslot * 8);
    }
  };

  STAGE(0, 0);
  for (int kt = 0; kt < 32; ++kt) {
    const int cur = kt & 1;
    if (kt < 31) {
      STAGE(kt + 1, cur ^ 1);
      asm volatile("s_waitcnt vmcnt(4)" ::: "memory");
    } else {
      asm volatile("s_waitcnt vmcnt(0)" ::: "memory");
    }
    __builtin_amdgcn_s_barrier();
    asm volatile("" ::: "memory");

    short8 af[4], bfr[4];
#pragma unroll
    for (int m = 0; m < 4; ++m)
      af[m] = *(const short8*)(As + cur * 4096 + (64 * wr + 16 * m + c) * 32 + g * 8);
#pragma unroll
    for (int n = 0; n < 4; ++n)
      bfr[n] = *(const short8*)(Bs + cur * 4096 + (64 * wc + 16 * n + c) * 32 + g * 8);
#pragma unroll
    for (int m = 0; m < 4; ++m)
#pragma unroll
      for (int n = 0; n < 4; ++n)
        acc[m][n] = mfma16(af[m], bfr[n], acc[m][n]);

    asm volatile("s_waitcnt lgkmcnt(0)" ::: "memory");
    __builtin_amdgcn_s_barrier();
  }
}

// ---------------- QKV projection (z: 0=Q(scaled), 1=K, 2=V transposed) -----

__global__ __launch_bounds__(256, 3) void proj_qkv(
    const __hip_bfloat16* __restrict__ xq, const __hip_bfloat16* __restrict__ xk,
    const __hip_bfloat16* __restrict__ xv,
    const __hip_bfloat16* __restrict__ wq, const __hip_bfloat16* __restrict__ wk,
    const __hip_bfloat16* __restrict__ wv,
    const float* __restrict__ bq, const float* __restrict__ bk,
    const float* __restrict__ bv,
    __hip_bfloat16* __restrict__ qh, __hip_bfloat16* __restrict__ kh,
    __hip_bfloat16* __restrict__ vtr) {
  __shared__ __hip_bfloat16 As[2 * 128 * 32];
  __shared__ __hip_bfloat16 Bs[2 * 128 * 32];
  const int z = blockIdx.z;
  const __hip_bfloat16* A = (z == 0) ? xq : ((z == 1) ? xk : xv);
  const __hip_bfloat16* W = (z == 0) ? wq : ((z == 1) ? wk : wv);
  const float* bias = (z == 0) ? bq : ((z == 1) ? bk : bv);
  const int nBase = blockIdx.x * 128;
  const int mBase = blockIdx.y * 128;

  f32x4 acc[4][4] = {};
  gemm_core(A, W, As, Bs, mBase, nBase, acc);

  const int t = threadIdx.x;
  const int lane = t & 63;
  const int w = t >> 6;
  const int wr = w >> 1, wc = w & 1;
  const int c = lane & 15, g = lane >> 4;

  if (z < 2) {
    __hip_bfloat16* O = (z == 0) ? qh : kh;
    // Q: 1/sqrt(Dh) * log2(e), so softmax is pure exp2
    const float scale = (z == 0) ? (0.125f * LOG2E) : 1.0f;
#pragma unroll
    for (int m = 0; m < 4; ++m) {
#pragma unroll
      for (int n = 0; n < 4; ++n) {
        const int row0 = mBase + 64 * wr + 16 * m + 4 * g;
        const int col = nBase + 64 * wc + 16 * n + c;
        const float bb = bias[col];
#pragma unroll
        for (int r = 0; r < 4; ++r)
          O[(size_t)(row0 + r) * 1024 + col] =
              __float2bfloat16((acc[m][n][r] + bb) * scale);
      }
    }
  } else {
    // V stored transposed per head: vtr[((b*16+h)*64+dh)*2048 + s]
#pragma unroll
    for (int m = 0; m < 4; ++m) {
#pragma unroll
      for (int n = 0; n < 4; ++n) {
        const int row0 = mBase + 64 * wr + 16 * m + 4 * g;  // global (b,s) row
        const int col = nBase + 64 * wc + 16 * n + c;       // d = h*64+dh
        const int bb = row0 >> 11;        // batch
        const int s0 = row0 & 2047;       // seq pos (4 consecutive)
        const float bv_ = bias[col];
        usv4 pk;
#pragma unroll
        for (int r = 0; r < 4; ++r) pk[r] = f2bf(acc[m][n][r] + bv_);
        *(usv4*)(vtr + ((size_t)(bb * 1024 + col)) * 2048 + s0) = pk;
      }
    }
  }
}

// ---------------- output projection (fp32 out + bias) ----------------

__global__ __launch_bounds__(256, 3) void out_proj(
    const __hip_bfloat16* __restrict__ ao, const __hip_bfloat16* __restrict__ wo,
    const float* __restrict__ bo, float* __restrict__ out) {
  __shared__ __hip_bfloat16 As[2 * 128 * 32];
  __shared__ __hip_bfloat16 Bs[2 * 128 * 32];
  const int nBase = blockIdx.x * 128;
  const int mBase = blockIdx.y * 128;

  f32x4 acc[4][4] = {};
  gemm_core(ao, wo, As, Bs, mBase, nBase, acc);

  const int t = threadIdx.x;
  const int lane = t & 63;
  const int w = t >> 6;
  const int wr = w >> 1, wc = w & 1;
  const int c = lane & 15, g = lane >> 4;
#pragma unroll
  for (int m = 0; m < 4; ++m) {
#pragma unroll
    for (int n = 0; n < 4; ++n) {
      const int row0 = mBase + 64 * wr + 16 * m + 4 * g;
      const int col = nBase + 64 * wc + 16 * n + c;
      const float bb = bo[col];
#pragma unroll
      for (int r = 0; r < 4; ++r)
        out[(size_t)(row0 + r) * 1024 + col] = acc[m][n][r] + bb;
    }
  }
}

// ---------------- flash attention, kv-split x2, 32x32 MFMA ----------------
// grid: 1024 flat = (16 qtiles, 32 bh, 2 kv-halves), XCD-swizzled.
// 4 waves; wave w owns q rows [qt*128+32w, +32); lane's q = lane&31 for
// accS (QK^T swapped) AND accO (PV swapped) -> softmax/rescale in-lane.
// KV tile 64, dbuf + vmcnt(4). P -> bf16 B-frags via cvt_pk + permlane32_swap.

__global__ __launch_bounds__(256, 3) void attn_partial(
    const __hip_bfloat16* __restrict__ qh, const __hip_bfloat16* __restrict__ kh,
    const __hip_bfloat16* __restrict__ vtr, __hip_bfloat16* __restrict__ po,
    float* __restrict__ Mbuf, float* __restrict__ Lbuf) {
  __shared__ __hip_bfloat16 Ks[2][64 * 64];   // [kv][d], slot-swizzled
  __shared__ __hip_bfloat16 Vs[2][64 * 64];   // [d][kv], slot-swizzled

  const int t = threadIdx.x;
  const int fid = blockIdx.x;
  const int xcd = fid & 7, idx = fid >> 3;
  const int bh = xcd * 4 + (idx & 3);
  const int qt = (idx >> 2) & 15;
  const int half = idx >> 6;
  const int b = bh >> 4, h = bh & 15;
  const int lane = t & 63;
  const int w = t >> 6;
  const int q32 = lane & 31;
  const int hi = lane >> 5;
  const int r7 = lane & 7;
  const size_t base = ((size_t)b * 2048) * 1024 + (size_t)h * 64;   // qh/kh/po
  const size_t vbase = ((size_t)(b * 1024 + h * 64)) * 2048;        // vtr
  const int halfBase = half * 1024;
  const int qrow = qt * 128 + 32 * w + q32;

  // Q B-fragments: qf[s] = Q[qrow][16s + 8hi .. +8) (pre-scaled by log2e/8)
  short8 qf[4];
#pragma unroll
  for (int s = 0; s < 4; ++s)
    qf[s] = *(const short8*)(qh + base + (size_t)qrow * 1024 + s * 16 + hi * 8);

  f32x16 accO[2];
#pragma unroll
  for (int jj = 0; jj < 2; ++jj) accO[jj] = (f32x16)(0.0f);
  float mreg = -1e30f, lreg = 0.f;

  const int srow = t >> 3, sslot = t & 7;

  auto STAGE = [&](int tile, int bufsel) {
    const int kbase = halfBase + tile * 64;
#pragma unroll
    for (int ii = 0; ii < 2; ++ii) {
      const int row = srow + 32 * ii;
      const int ss = sslot ^ (row & 7);   // source-side swizzle (involution)
      gload_lds16(kh + base + (size_t)(kbase + row) * 1024 + ss * 8,
                  &Ks[bufsel][row * 64 + sslot * 8]);
      gload_lds16(vtr + vbase + (size_t)row * 2048 + kbase + ss * 8,
                  &Vs[bufsel][row * 64 + sslot * 8]);
    }
  };

  STAGE(0, 0);

  for (int tt = 0; tt < 16; ++tt) {
    const int cur = tt & 1;
    if (tt < 15) {
      STAGE(tt + 1, cur ^ 1);
      asm volatile("s_waitcnt vmcnt(4)" ::: "memory");
    } else {
      asm volatile("s_waitcnt vmcnt(0)" ::: "memory");
    }
    __builtin_amdgcn_s_barrier();
    asm volatile("" ::: "memory");

    // QK^T swapped: A = K rows (kv), B = Q cols (q). Lane holds, per sub,
    // S[kv = 32sub + 4hi + (reg&3) + 8*(reg>>2)][q = q32].
    f32x16 accS[2];
#pragma unroll
    for (int sub = 0; sub < 2; ++sub) accS[sub] = (f32x16)(0.0f);
    __builtin_amdgcn_s_setprio(1);
#pragma unroll
    for (int sub = 0; sub < 2; ++sub) {
      const int row = 32 * sub + q32;
#pragma unroll
      for (int s = 0; s < 4; ++s) {
        const int slot = (2 * s + hi) ^ r7;
        const short8 kf = *(const short8*)(&Ks[cur][row * 64 + slot * 8]);
        accS[sub] = mfma32(kf, qf[s], accS[sub]);
      }
    }
    __builtin_amdgcn_s_setprio(0);

    // online softmax, fully in-lane (one q per lane; scores in log2 units)
    float pm[4] = {-1e30f, -1e30f, -1e30f, -1e30f};
#pragma unroll
    for (int sub = 0; sub < 2; ++sub)
#pragma unroll
      for (int rg = 0; rg < 16; ++rg) pm[rg & 3] = fmaxf(pm[rg & 3], accS[sub][rg]);
    float pmax = fmaxf(fmaxf(pm[0], pm[1]), fmaxf(pm[2], pm[3]));
    pmax = fmaxf(pmax, __shfl_xor(pmax, 32, 64));

    // defer-max (T13): only rescale when the max grew materially
    if (!__all(pmax - mreg <= 11.0f)) {
      const float mn = fmaxf(mreg, pmax);
      const float corr = exp2f(mreg - mn);
      mreg = mn;
      lreg *= corr;
#pragma unroll
      for (int jj = 0; jj < 2; ++jj)
#pragma unroll
        for (int rg = 0; rg < 16; ++rg) accO[jj][rg] *= corr;
    }

    float rs[4] = {0.f, 0.f, 0.f, 0.f};
#pragma unroll
    for (int sub = 0; sub < 2; ++sub)
#pragma unroll
      for (int rg = 0; rg < 16; ++rg) {
        const float p = exp2f(accS[sub][rg] - mreg);
        accS[sub][rg] = p;
        rs[rg & 3] += p;
      }
    float rsum = (rs[0] + rs[1]) + (rs[2] + rs[3]);
    rsum += __shfl_xor(rsum, 32, 64);
    lreg += rsum;

    // P -> PV B-fragments: 4 cvt_pk + 2 permlane32_swap per (sub, tstep).
    // B-frag lane (q32,hi) needs kv = 32sub + 16t + 8hi + j (j=0..7).
    short8 pb[2][2];
#pragma unroll
    for (int sub = 0; sub < 2; ++sub)
#pragma unroll
      for (int t2 = 0; t2 < 2; ++t2) {
        unsigned a  = cvt_pk(accS[sub][8 * t2 + 0], accS[sub][8 * t2 + 1]);
        unsigned a2 = cvt_pk(accS[sub][8 * t2 + 2], accS[sub][8 * t2 + 3]);
        unsigned bb = cvt_pk(accS[sub][8 * t2 + 4], accS[sub][8 * t2 + 5]);
        unsigned b2 = cvt_pk(accS[sub][8 * t2 + 6], accS[sub][8 * t2 + 7]);
        asm("v_permlane32_swap_b32 %0, %1" : "+v"(a), "+v"(bb));
        asm("v_permlane32_swap_b32 %0, %1" : "+v"(a2), "+v"(b2));
        union { unsigned u[4]; short8 v; } uu;
        uu.u[0] = a; uu.u[1] = a2; uu.u[2] = bb; uu.u[3] = b2;
        pb[sub][t2] = uu.v;
      }

    // PV swapped: A = V^T rows (d), B = P cols (q) -> accO col = q (in-lane!)
    __builtin_amdgcn_s_setprio(1);
#pragma unroll
    for (int jj = 0; jj < 2; ++jj) {
      const int dl = 32 * jj + q32;
#pragma unroll
      for (int sub = 0; sub < 2; ++sub)
#pragma unroll
        for (int t2 = 0; t2 < 2; ++t2) {
          const int kslot = (4 * sub + 2 * t2 + hi) ^ r7;
          const short8 vf = *(const short8*)(&Vs[cur][dl * 64 + kslot * 8]);
          accO[jj] = mfma32(vf, pb[sub][t2], accO[jj]);
        }
    }
    __builtin_amdgcn_s_setprio(0);

    asm volatile("s_waitcnt lgkmcnt(0)" ::: "memory");
    __builtin_amdgcn_s_barrier();
  }

  // epilogue: normalized partial O (bf16) + per-row m,l.
  // accO[jj] lane (q32,hi) reg (r+4s) -> O^T[d = 32jj + 8s + 4hi + r][qrow]
  const float linv = 1.0f / lreg;
#pragma unroll
  for (int jj = 0; jj < 2; ++jj)
#pragma unroll
    for (int s = 0; s < 4; ++s) {
      usv4 pk;
#pragma unroll
      for (int r = 0; r < 4; ++r) pk[r] = f2bf(accO[jj][4 * s + r] * linv);
      *(usv4*)(po + (size_t)half * NXC + base + (size_t)qrow * 1024 +
               32 * jj + 8 * s + 4 * hi) = pk;
    }
  if (lane < 32) {
    const int off = half * 65536 + bh * 2048 + qrow;
    Mbuf[off] = mreg;
    Lbuf[off] = lreg;
  }
}

// ---------------- merge the two kv-half partials ----------------

__global__ __launch_bounds__(256) void attn_merge(
    const __hip_bfloat16* __restrict__ po, const float* __restrict__ Mbuf,
    const float* __restrict__ Lbuf, __hip_bfloat16* __restrict__ ao) {
  const size_t e = ((size_t)blockIdx.x * 256 + threadIdx.x) * 8;
  const int srow = (int)(e >> 10);
  const int d0 = (int)(e & 1023);
  const int b = srow >> 11, s = srow & 2047;
  const int h = d0 >> 6;
  const int idx = (b * 16 + h) * 2048 + s;
  const float m0 = Mbuf[idx], m1 = Mbuf[65536 + idx];
  const float l0 = Lbuf[idx], l1 = Lbuf[65536 + idx];
  const float Mx = fmaxf(m0, m1);
  float w0 = exp2f(m0 - Mx) * l0;
  float w1 = exp2f(m1 - Mx) * l1;
  const float inv = 1.0f / (w0 + w1);
  w0 *= inv; w1 *= inv;
  const short8 x0 = *(const short8*)(po + e);
  const short8 x1 = *(const short8*)(po + NXC + e);
  short8 o;
#pragma unroll
  for (int j = 0; j < 8; ++j) {
    const float v = w0 * bf2f((unsigned short)x0[j]) +
                    w1 * bf2f((unsigned short)x1[j]);
    o[j] = (short)f2bf(v);
  }
  *(short8*)(ao + e) = o;
}

// ---------------- launch ----------------

extern "C" void kernel_launch(void* const* d_in, const int* in_sizes, int n_in,
                              void* d_out, int out_size, void* d_ws, size_t ws_size,
                              hipStream_t stream) {
  (void)in_sizes; (void)n_in; (void)out_size; (void)ws_size;
  const float* query = (const float*)d_in[0];
  const float* key_  = (const float*)d_in[1];
  const float* value = (const float*)d_in[2];
  const float* Wq = (const float*)d_in[3];
  const float* bq = (const float*)d_in[4];
  const float* Wk = (const float*)d_in[5];
  const float* bk = (const float*)d_in[6];
  const float* Wv = (const float*)d_in[7];
  const float* bv = (const float*)d_in[8];
  const float* Wo = (const float*)d_in[9];
  const float* bo = (const float*)d_in[10];

  const size_t NX = NXC;                   // per converted input / activation
  const size_t NW = (size_t)1024 * 1024;   // per converted weight
  __hip_bfloat16* ws  = (__hip_bfloat16*)d_ws;
  __hip_bfloat16* xq  = ws;                // xq,xk,xv contiguous (3*NX)
  __hip_bfloat16* wqb = ws + 3 * NX;       // wq,wk,wv,wo contiguous (4*NW)
  __hip_bfloat16* qh  = wqb + 4 * NW;
  __hip_bfloat16* kh  = qh + NX;
  __hip_bfloat16* vtr = kh + NX;           // [b][h][dh][s]
  __hip_bfloat16* ao  = vtr + NX;          // [b][s][h*64+dh]
  // after proj_qkv, xq/xk/xv are dead: reuse for attention partials
  __hip_bfloat16* po = ws;                 // [2][b][s][h*64+dh] (2*NX el)
  float* Mf = (float*)(ws + 2 * NX);       // [2][32][2048]
  float* Lf = Mf + 131072;
  // total ws use: 64 MiB

  cvt_inputs<<<dim3(2048, 3), 256, 0, stream>>>(query, key_, value, xq);
  cvt_weights<<<dim3(512, 4), 256, 0, stream>>>(Wq, Wk, Wv, Wo, wqb);
  proj_qkv<<<dim3(8, 32, 3), 256, 0, stream>>>(
      xq, xq + NX, xq + 2 * NX, wqb, wqb + NW, wqb + 2 * NW,
      bq, bk, bv, qh, kh, vtr);
  attn_partial<<<dim3(1024), 256, 0, stream>>>(qh, kh, vtr, po, Mf, Lf);
  attn_merge<<<dim3(2048), 256, 0, stream>>>(po, Mf, Lf, ao);
  out_proj<<<dim3(8, 32), 256, 0, stream>>>(ao, wqb + 3 * NW, bo, (float*)d_out);
}

// Round 4
// 246.291 us; speedup vs baseline: 1.2987x; 1.0094x over previous
//
#include <hip/hip_runtime.h>
#include <hip/hip_bf16.h>
#include <stdint.h>
#include <stddef.h>

// MHA forward, B=2 S=2048 D=1024 H=16 Dh=64, bf16 MFMA pipeline.
// cvt(fp32->bf16) -> proj QKV (256^2-tile 8-wave phase-split pipelined GEMM,
// counted vmcnt, swizzled LDS; V stored transposed per head; Q pre-scaled by
// log2e/sqrt(Dh)) -> flash attention kv-split x2 (32x32 MFMA, swapped QK^T and
// swapped PV, in-register softmax, cvt_pk+permlane32, defer-max, setprio)
// -> merge partials -> output proj (128^2 2-phase GEMM, fp32 out).

typedef __attribute__((ext_vector_type(8))) short short8;   // 8 x bf16
typedef __attribute__((ext_vector_type(4))) float f32x4;    // 16x16 MFMA C/D
typedef __attribute__((ext_vector_type(16))) float f32x16;  // 32x32 MFMA C/D
typedef __attribute__((ext_vector_type(4))) unsigned short usv4;

#define DEVFN static __device__ __forceinline__

constexpr float LOG2E = 1.44269504088896340736f;
constexpr size_t NXC = 4194304;   // 4096*1024 elements

DEVFN f32x4 mfma16(short8 a, short8 b, f32x4 c) {
  return __builtin_amdgcn_mfma_f32_16x16x32_bf16(a, b, c, 0, 0, 0);
}

DEVFN f32x16 mfma32(short8 a, short8 b, f32x16 c) {
  return __builtin_amdgcn_mfma_f32_32x32x16_bf16(a, b, c, 0, 0, 0);
}

// async global->LDS, 16B per lane. Dest must be linear in lane id.
DEVFN void gload_lds16(const void* g, void* l) {
  __builtin_amdgcn_global_load_lds(
      (const __attribute__((address_space(1))) unsigned int*)g,
      (__attribute__((address_space(3))) unsigned int*)l, 16, 0, 0);
}

DEVFN unsigned short f2bf(float x) {
  union { __hip_bfloat16 h; unsigned short u; } cv;
  cv.h = __float2bfloat16(x);
  return cv.u;
}

DEVFN float bf2f(unsigned short u) {
  union { unsigned int i; float f; } cv;
  cv.i = ((unsigned int)u) << 16;
  return cv.f;
}

DEVFN unsigned cvt_pk(float lo, float hi) {   // u32 = {bf16(lo), bf16(hi)<<16}
  unsigned r;
  asm("v_cvt_pk_bf16_f32 %0, %1, %2" : "=v"(r) : "v"(lo), "v"(hi));
  return r;
}

DEVFN short8 cvt8(const float* s) {
  float4 a = *(const float4*)(s);
  float4 b = *(const float4*)(s + 4);
  short8 o;
  o[0] = (short)f2bf(a.x); o[1] = (short)f2bf(a.y);
  o[2] = (short)f2bf(a.z); o[3] = (short)f2bf(a.w);
  o[4] = (short)f2bf(b.x); o[5] = (short)f2bf(b.y);
  o[6] = (short)f2bf(b.z); o[7] = (short)f2bf(b.w);
  return o;
}

// ---------------- fp32 -> bf16 conversion ----------------

__global__ __launch_bounds__(256) void cvt_inputs(
    const float* __restrict__ s0, const float* __restrict__ s1,
    const float* __restrict__ s2, __hip_bfloat16* __restrict__ dst) {
  const int y = blockIdx.y;
  const float* s = (y == 0) ? s0 : ((y == 1) ? s1 : s2);
  __hip_bfloat16* d = dst + (size_t)y * NXC;
  const size_t i = ((size_t)blockIdx.x * 256 + threadIdx.x) * 8;
  *(short8*)(d + i) = cvt8(s + i);
}

__global__ __launch_bounds__(256) void cvt_weights(
    const float* __restrict__ s0, const float* __restrict__ s1,
    const float* __restrict__ s2, const float* __restrict__ s3,
    __hip_bfloat16* __restrict__ dst) {
  const int y = blockIdx.y;
  const float* s = (y == 0) ? s0 : (y == 1) ? s1 : (y == 2) ? s2 : s3;
  __hip_bfloat16* d = dst + (size_t)y * (1024u * 1024u);
  const size_t i = ((size_t)blockIdx.x * 256 + threadIdx.x) * 8;
  *(short8*)(d + i) = cvt8(s + i);
}

// ---- 256x256 NT GEMM, 8 waves (2M x 4N), BK=64, K-tile dbuf, 4 phases ----
// Per wave: output 128x64 (acc[8][4]); per K-tile 64 MFMA in 4 clusters of 16.
// LDS 128KB dynamic: [2 bufs][A 256x64 | B 256x64] bf16, chunk^= (row&7)
// swizzle (pre-swizzled global source; read applies same involution).
// Counted vmcnt(8): each wave stages only the 8 chunks (1KB each) of its own
// A-half/B-half for tile t+1 at the top of tile t, then waits only tile t's.

__global__ __launch_bounds__(512, 2) void proj256(
    const __hip_bfloat16* __restrict__ xq, const __hip_bfloat16* __restrict__ xk,
    const __hip_bfloat16* __restrict__ xv,
    const __hip_bfloat16* __restrict__ wq, const __hip_bfloat16* __restrict__ wk,
    const __hip_bfloat16* __restrict__ wv,
    const float* __restrict__ bq, const float* __restrict__ bk,
    const float* __restrict__ bv,
    __hip_bfloat16* __restrict__ qh, __hip_bfloat16* __restrict__ kh,
    __hip_bfloat16* __restrict__ vtr) {
  extern __shared__ __hip_bfloat16 smem[];   // 2 x (16384 A + 16384 B)

  const int t512 = threadIdx.x;
  const int lane = t512 & 63;
  const int w = t512 >> 6;                 // 0..7
  const int wm = w >> 2, wn = w & 3;       // wave tile: rows 128*wm, cols 64*wn
  const int bhf = wn >> 1;                 // B-half this wave consumes
  const int c = lane & 15, g = lane >> 4;
  const int c7 = c & 7;
  const int l8 = lane >> 3;                // 0..7
  const int sk = (lane & 7) ^ l8;          // pre-swizzled global k-chunk

  // block swizzle: 192 blocks, 8 XCDs x 24
  const int bid = blockIdx.x;
  const int sid = (bid & 7) * 24 + (bid >> 3);
  const int z = sid >> 6;
  const int rem = sid & 63;
  const int mBase = (rem >> 2) * 256;
  const int nBase = (rem & 3) * 256;

  const __hip_bfloat16* A = (z == 0) ? xq : ((z == 1) ? xk : xv);
  const __hip_bfloat16* W = (z == 0) ? wq : ((z == 1) ? wk : wv);
  const float* bias = (z == 0) ? bq : ((z == 1) ? bk : bv);

  // stage addressing (per-wave ownership: 4 chunks of its A-half + 4 of B-half)
  const int rowA0 = 128 * wm + wn * 32;                  // + i*8 + l8
  const int rowB0 = 128 * bhf + (2 * wm + (wn & 1)) * 32;
  const int ldsA0 = rowA0 * 64;
  const int ldsB0 = 16384 + rowB0 * 64;
  const __hip_bfloat16* gA = A + (size_t)(mBase + rowA0 + l8) * 1024 + sk * 8;
  const __hip_bfloat16* gB = W + (size_t)(nBase + rowB0 + l8) * 1024 + sk * 8;

  auto STAGE = [&](int tile, int sel2) {
    __hip_bfloat16* db = smem + sel2 * 32768;
    const __hip_bfloat16* sa = gA + tile * 64;
    const __hip_bfloat16* sb = gB + tile * 64;
#pragma unroll
    for (int i = 0; i < 4; ++i) {
      gload_lds16(sa + i * 8192, db + ldsA0 + i * 512 + lane * 8);
      gload_lds16(sb + i * 8192, db + ldsB0 + i * 512 + lane * 8);
    }
  };

  f32x4 acc[8][4] = {};
  short8 af[4][2];    // current m-half fragments [m][kk]
  short8 bfr[4][2];   // all 4 n fragments       [n][kk]

  // fragment read offsets (swizzled): chunk (kk*4+g)^c7
  const int ck0 = ((0 * 4 + g) ^ c7) * 8;
  const int ck1 = ((1 * 4 + g) ^ c7) * 8;
  const int aRow = (128 * wm + c) * 64;     // + m*1024
  const int bRow = 16384 + (64 * wn + 16 * 0 + c) * 64;  // + n*1024

  STAGE(0, 0);

  for (int t = 0; t < 16; ++t) {
    const int sel = t & 1;
    const __hip_bfloat16* Lb = smem + sel * 32768;
    if (t < 15) {
      STAGE(t + 1, sel ^ 1);
      asm volatile("s_waitcnt vmcnt(8)" ::: "memory");
    } else {
      asm volatile("s_waitcnt vmcnt(0)" ::: "memory");
    }
    __builtin_amdgcn_s_barrier();
    asm volatile("" ::: "memory");

    // ph1: read A mh0 (8) + B nh0 (4); MFMA m0-3 x n0-1
#pragma unroll
    for (int m = 0; m < 4; ++m) {
      af[m][0] = *(const short8*)(Lb + aRow + m * 1024 + ck0);
      af[m][1] = *(const short8*)(Lb + aRow + m * 1024 + ck1);
    }
#pragma unroll
    for (int n = 0; n < 2; ++n) {
      bfr[n][0] = *(const short8*)(Lb + bRow + n * 1024 + ck0);
      bfr[n][1] = *(const short8*)(Lb + bRow + n * 1024 + ck1);
    }
    __builtin_amdgcn_s_setprio(1);
#pragma unroll
    for (int kk = 0; kk < 2; ++kk)
#pragma unroll
      for (int m = 0; m < 4; ++m)
#pragma unroll
        for (int n = 0; n < 2; ++n)
          acc[m][n] = mfma16(af[m][kk], bfr[n][kk], acc[m][n]);
    __builtin_amdgcn_s_setprio(0);
    __builtin_amdgcn_s_barrier();
    asm volatile("" ::: "memory");

    // ph2: read B nh1 (4); MFMA m0-3 x n2-3
#pragma unroll
    for (int n = 2; n < 4; ++n) {
      bfr[n][0] = *(const short8*)(Lb + bRow + n * 1024 + ck0);
      bfr[n][1] = *(const short8*)(Lb + bRow + n * 1024 + ck1);
    }
    __builtin_amdgcn_s_setprio(1);
#pragma unroll
    for (int kk = 0; kk < 2; ++kk)
#pragma unroll
      for (int m = 0; m < 4; ++m)
#pragma unroll
        for (int n = 2; n < 4; ++n)
          acc[m][n] = mfma16(af[m][kk], bfr[n][kk], acc[m][n]);
    __builtin_amdgcn_s_setprio(0);
    __builtin_amdgcn_s_barrier();
    asm volatile("" ::: "memory");

    // ph3: read A mh1 (8); MFMA m4-7 x n2-3
#pragma unroll
    for (int m = 0; m < 4; ++m) {
      af[m][0] = *(const short8*)(Lb + aRow + (m + 4) * 1024 + ck0);
      af[m][1] = *(const short8*)(Lb + aRow + (m + 4) * 1024 + ck1);
    }
    __builtin_amdgcn_s_setprio(1);
#pragma unroll
    for (int kk = 0; kk < 2; ++kk)
#pragma unroll
      for (int m = 0; m < 4; ++m)
#pragma unroll
        for (int n = 2; n < 4; ++n)
          acc[m + 4][n] = mfma16(af[m][kk], bfr[n][kk], acc[m + 4][n]);
    __builtin_amdgcn_s_setprio(0);
    __builtin_amdgcn_s_barrier();
    asm volatile("" ::: "memory");

    // ph4: MFMA m4-7 x n0-1 (all operands live in regs; no barrier after)
    __builtin_amdgcn_s_setprio(1);
#pragma unroll
    for (int kk = 0; kk < 2; ++kk)
#pragma unroll
      for (int m = 0; m < 4; ++m)
#pragma unroll
        for (int n = 0; n < 2; ++n)
          acc[m + 4][n] = mfma16(af[m][kk], bfr[n][kk], acc[m + 4][n]);
    __builtin_amdgcn_s_setprio(0);
  }

  // epilogue
  if (z < 2) {
    __hip_bfloat16* O = (z == 0) ? qh : kh;
    const float scale = (z == 0) ? (0.125f * LOG2E) : 1.0f;
#pragma unroll
    for (int m = 0; m < 8; ++m) {
#pragma unroll
      for (int n = 0; n < 4; ++n) {
        const int row0 = mBase + 128 * wm + 16 * m + 4 * g;
        const int col = nBase + 64 * wn + 16 * n + c;
        const float bb = bias[col];
#pragma unroll
        for (int r = 0; r < 4; ++r)
          O[(size_t)(row0 + r) * 1024 + col] =
              __float2bfloat16((acc[m][n][r] + bb) * scale);
      }
    }
  } else {
    // V transposed per head: vtr[((b*16+h)*64+dh)*2048 + s]
#pragma unroll
    for (int m = 0; m < 8; ++m) {
#pragma unroll
      for (int n = 0; n < 4; ++n) {
        const int row0 = mBase + 128 * wm + 16 * m + 4 * g;  // (b,s) row
        const int col = nBase + 64 * wn + 16 * n + c;        // d = h*64+dh
        const int bb = row0 >> 11;
        const int s0 = row0 & 2047;
        const float bv_ = bias[col];
        usv4 pk;
#pragma unroll
        for (int r = 0; r < 4; ++r) pk[r] = f2bf(acc[m][n][r] + bv_);
        *(usv4*)(vtr + ((size_t)(bb * 1024 + col)) * 2048 + s0) = pk;
      }
    }
  }
}

// ------- 128x128 NT GEMM core (K=1024, BK=32, dbuf + counted vmcnt) -------

DEVFN void gemm_core(const __hip_bfloat16* __restrict__ A,
                     const __hip_bfloat16* __restrict__ W,
                     __hip_bfloat16* As, __hip_bfloat16* Bs,
                     int mBase, int nBase, f32x4 (&acc)[4][4]) {
  const int t = threadIdx.x;
  const int lane = t & 63;
  const int w = t >> 6;
  const int wr = w >> 1, wc = w & 1;
  const int c = lane & 15, g = lane >> 4;
  const int srow = t >> 2, sslot = t & 3;

  auto STAGE = [&](int kt, int bufsel) {
    const int k0 = kt * 32;
#pragma unroll
    for (int inst = 0; inst < 2; ++inst) {
      const int row = 64 * inst + srow;
      gload_lds16(A + (size_t)(mBase + row) * 1024 + k0 + sslot * 8,
                  As + bufsel * 4096 + row * 32 + sslot * 8);
      gload_lds16(W + (size_t)(nBase + row) * 1024 + k0 + sslot * 8,
                  Bs + bufsel * 4096 + row * 32 + sslot * 8);
    }
  };

  STAGE(0, 0);
  for (int kt = 0; kt < 32; ++kt) {
    const int cur = kt & 1;
    if (kt < 31) {
      STAGE(kt + 1, cur ^ 1);
      asm volatile("s_waitcnt vmcnt(4)" ::: "memory");
    } else {
      asm volatile("s_waitcnt vmcnt(0)" ::: "memory");
    }
    __builtin_amdgcn_s_barrier();
    asm volatile("" ::: "memory");

    short8 af[4], bfr[4];
#pragma unroll
    for (int m = 0; m < 4; ++m)
      af[m] = *(const short8*)(As + cur * 4096 + (64 * wr + 16 * m + c) * 32 + g * 8);
#pragma unroll
    for (int n = 0; n < 4; ++n)
      bfr[n] = *(const short8*)(Bs + cur * 4096 + (64 * wc + 16 * n + c) * 32 + g * 8);
#pragma unroll
    for (int m = 0; m < 4; ++m)
#pragma unroll
      for (int n = 0; n < 4; ++n)
        acc[m][n] = mfma16(af[m], bfr[n], acc[m][n]);

    asm volatile("s_waitcnt lgkmcnt(0)" ::: "memory");
    __builtin_amdgcn_s_barrier();
  }
}

// ---------------- output projection (fp32 out + bias) ----------------

__global__ __launch_bounds__(256, 3) void out_proj(
    const __hip_bfloat16* __restrict__ ao, const __hip_bfloat16* __restrict__ wo,
    const float* __restrict__ bo, float* __restrict__ out) {
  __shared__ __hip_bfloat16 As[2 * 128 * 32];
  __shared__ __hip_bfloat16 Bs[2 * 128 * 32];
  const int nBase = blockIdx.x * 128;
  const int mBase = blockIdx.y * 128;

  f32x4 acc[4][4] = {};
  gemm_core(ao, wo, As, Bs, mBase, nBase, acc);

  const int t = threadIdx.x;
  const int lane = t & 63;
  const int w = t >> 6;
  const int wr = w >> 1, wc = w & 1;
  const int c = lane & 15, g = lane >> 4;
#pragma unroll
  for (int m = 0; m < 4; ++m) {
#pragma unroll
    for (int n = 0; n < 4; ++n) {
      const int row0 = mBase + 64 * wr + 16 * m + 4 * g;
      const int col = nBase + 64 * wc + 16 * n + c;
      const float bb = bo[col];
#pragma unroll
      for (int r = 0; r < 4; ++r)
        out[(size_t)(row0 + r) * 1024 + col] = acc[m][n][r] + bb;
    }
  }
}

// ---------------- flash attention, kv-split x2, 32x32 MFMA ----------------

__global__ __launch_bounds__(256, 3) void attn_partial(
    const __hip_bfloat16* __restrict__ qh, const __hip_bfloat16* __restrict__ kh,
    const __hip_bfloat16* __restrict__ vtr, __hip_bfloat16* __restrict__ po,
    float* __restrict__ Mbuf, float* __restrict__ Lbuf) {
  __shared__ __hip_bfloat16 Ks[2][64 * 64];   // [kv][d], slot-swizzled
  __shared__ __hip_bfloat16 Vs[2][64 * 64];   // [d][kv], slot-swizzled

  const int t = threadIdx.x;
  const int fid = blockIdx.x;
  const int xcd = fid & 7, idx = fid >> 3;
  const int bh = xcd * 4 + (idx & 3);
  const int qt = (idx >> 2) & 15;
  const int half = idx >> 6;
  const int b = bh >> 4, h = bh & 15;
  const int lane = t & 63;
  const int w = t >> 6;
  const int q32 = lane & 31;
  const int hi = lane >> 5;
  const int r7 = lane & 7;
  const size_t base = ((size_t)b * 2048) * 1024 + (size_t)h * 64;   // qh/kh/po
  const size_t vbase = ((size_t)(b * 1024 + h * 64)) * 2048;        // vtr
  const int halfBase = half * 1024;
  const int qrow = qt * 128 + 32 * w + q32;

  // Q B-fragments: qf[s] = Q[qrow][16s + 8hi .. +8) (pre-scaled by log2e/8)
  short8 qf[4];
#pragma unroll
  for (int s = 0; s < 4; ++s)
    qf[s] = *(const short8*)(qh + base + (size_t)qrow * 1024 + s * 16 + hi * 8);

  f32x16 accO[2];
#pragma unroll
  for (int jj = 0; jj < 2; ++jj) accO[jj] = (f32x16)(0.0f);
  float mreg = -1e30f, lreg = 0.f;

  const int srow = t >> 3, sslot = t & 7;

  auto STAGE = [&](int tile, int bufsel) {
    const int kbase = halfBase + tile * 64;
#pragma unroll
    for (int ii = 0; ii < 2; ++ii) {
      const int row = srow + 32 * ii;
      const int ss = sslot ^ (row & 7);   // source-side swizzle (involution)
      gload_lds16(kh + base + (size_t)(kbase + row) * 1024 + ss * 8,
                  &Ks[bufsel][row * 64 + sslot * 8]);
      gload_lds16(vtr + vbase + (size_t)row * 2048 + kbase + ss * 8,
                  &Vs[bufsel][row * 64 + sslot * 8]);
    }
  };

  STAGE(0, 0);

  for (int tt = 0; tt < 16; ++tt) {
    const int cur = tt & 1;
    if (tt < 15) {
      STAGE(tt + 1, cur ^ 1);
      asm volatile("s_waitcnt vmcnt(4)" ::: "memory");
    } else {
      asm volatile("s_waitcnt vmcnt(0)" ::: "memory");
    }
    __builtin_amdgcn_s_barrier();
    asm volatile("" ::: "memory");

    // QK^T swapped: A = K rows (kv), B = Q cols (q)
    f32x16 accS[2];
#pragma unroll
    for (int sub = 0; sub < 2; ++sub) accS[sub] = (f32x16)(0.0f);
    __builtin_amdgcn_s_setprio(1);
#pragma unroll
    for (int sub = 0; sub < 2; ++sub) {
      const int row = 32 * sub + q32;
#pragma unroll
      for (int s = 0; s < 4; ++s) {
        const int slot = (2 * s + hi) ^ r7;
        const short8 kf = *(const short8*)(&Ks[cur][row * 64 + slot * 8]);
        accS[sub] = mfma32(kf, qf[s], accS[sub]);
      }
    }
    __builtin_amdgcn_s_setprio(0);

    // online softmax, fully in-lane
    float pm[4] = {-1e30f, -1e30f, -1e30f, -1e30f};
#pragma unroll
    for (int sub = 0; sub < 2; ++sub)
#pragma unroll
      for (int rg = 0; rg < 16; ++rg) pm[rg & 3] = fmaxf(pm[rg & 3], accS[sub][rg]);
    float pmax = fmaxf(fmaxf(pm[0], pm[1]), fmaxf(pm[2], pm[3]));
    pmax = fmaxf(pmax, __shfl_xor(pmax, 32, 64));

    if (!__all(pmax - mreg <= 11.0f)) {
      const float mn = fmaxf(mreg, pmax);
      const float corr = exp2f(mreg - mn);
      mreg = mn;
      lreg *= corr;
#pragma unroll
      for (int jj = 0; jj < 2; ++jj)
#pragma unroll
        for (int rg = 0; rg < 16; ++rg) accO[jj][rg] *= corr;
    }

    float rs[4] = {0.f, 0.f, 0.f, 0.f};
#pragma unroll
    for (int sub = 0; sub < 2; ++sub)
#pragma unroll
      for (int rg = 0; rg < 16; ++rg) {
        const float p = exp2f(accS[sub][rg] - mreg);
        accS[sub][rg] = p;
        rs[rg & 3] += p;
      }
    float rsum = (rs[0] + rs[1]) + (rs[2] + rs[3]);
    rsum += __shfl_xor(rsum, 32, 64);
    lreg += rsum;

    // P -> PV B-fragments via cvt_pk + permlane32_swap
    short8 pb[2][2];
#pragma unroll
    for (int sub = 0; sub < 2; ++sub)
#pragma unroll
      for (int t2 = 0; t2 < 2; ++t2) {
        unsigned a  = cvt_pk(accS[sub][8 * t2 + 0], accS[sub][8 * t2 + 1]);
        unsigned a2 = cvt_pk(accS[sub][8 * t2 + 2], accS[sub][8 * t2 + 3]);
        unsigned bb = cvt_pk(accS[sub][8 * t2 + 4], accS[sub][8 * t2 + 5]);
        unsigned b2 = cvt_pk(accS[sub][8 * t2 + 6], accS[sub][8 * t2 + 7]);
        asm("v_permlane32_swap_b32 %0, %1" : "+v"(a), "+v"(bb));
        asm("v_permlane32_swap_b32 %0, %1" : "+v"(a2), "+v"(b2));
        union { unsigned u[4]; short8 v; } uu;
        uu.u[0] = a; uu.u[1] = a2; uu.u[2] = bb; uu.u[3] = b2;
        pb[sub][t2] = uu.v;
      }

    // PV swapped: A = V^T rows (d), B = P cols (q) -> accO col = q (in-lane)
    __builtin_amdgcn_s_setprio(1);
#pragma unroll
    for (int jj = 0; jj < 2; ++jj) {
      const int dl = 32 * jj + q32;
#pragma unroll
      for (int sub = 0; sub < 2; ++sub)
#pragma unroll
        for (int t2 = 0; t2 < 2; ++t2) {
          const int kslot = (4 * sub + 2 * t2 + hi) ^ r7;
          const short8 vf = *(const short8*)(&Vs[cur][dl * 64 + kslot * 8]);
          accO[jj] = mfma32(vf, pb[sub][t2], accO[jj]);
        }
    }
    __builtin_amdgcn_s_setprio(0);

    asm volatile("s_waitcnt lgkmcnt(0)" ::: "memory");
    __builtin_amdgcn_s_barrier();
  }

  // epilogue: normalized partial O (bf16) + per-row m,l
  const float linv = 1.0f / lreg;
#pragma unroll
  for (int jj = 0; jj < 2; ++jj)
#pragma unroll
    for (int s = 0; s < 4; ++s) {
      usv4 pk;
#pragma unroll
      for (int r = 0; r < 4; ++r) pk[r] = f2bf(accO[jj][4 * s + r] * linv);
      *(usv4*)(po + (size_t)half * NXC + base + (size_t)qrow * 1024 +
               32 * jj + 8 * s + 4 * hi) = pk;
    }
  if (lane < 32) {
    const int off = half * 65536 + bh * 2048 + qrow;
    Mbuf[off] = mreg;
    Lbuf[off] = lreg;
  }
}

// ---------------- merge the two kv-half partials ----------------

__global__ __launch_bounds__(256) void attn_merge(
    const __hip_bfloat16* __restrict__ po, const float* __restrict__ Mbuf,
    const float* __restrict__ Lbuf, __hip_bfloat16* __restrict__ ao) {
  const size_t e = ((size_t)blockIdx.x * 256 + threadIdx.x) * 8;
  const int srow = (int)(e >> 10);
  const int d0 = (int)(e & 1023);
  const int b = srow >> 11, s = srow & 2047;
  const int h = d0 >> 6;
  const int idx = (b * 16 + h) * 2048 + s;
  const float m0 = Mbuf[idx], m1 = Mbuf[65536 + idx];
  const float l0 = Lbuf[idx], l1 = Lbuf[65536 + idx];
  const float Mx = fmaxf(m0, m1);
  float w0 = exp2f(m0 - Mx) * l0;
  float w1 = exp2f(m1 - Mx) * l1;
  const float inv = 1.0f / (w0 + w1);
  w0 *= inv; w1 *= inv;
  const short8 x0 = *(const short8*)(po + e);
  const short8 x1 = *(const short8*)(po + NXC + e);
  short8 o;
#pragma unroll
  for (int j = 0; j < 8; ++j) {
    const float v = w0 * bf2f((unsigned short)x0[j]) +
                    w1 * bf2f((unsigned short)x1[j]);
    o[j] = (short)f2bf(v);
  }
  *(short8*)(ao + e) = o;
}

// ---------------- launch ----------------

extern "C" void kernel_launch(void* const* d_in, const int* in_sizes, int n_in,
                              void* d_out, int out_size, void* d_ws, size_t ws_size,
                              hipStream_t stream) {
  (void)in_sizes; (void)n_in; (void)out_size; (void)ws_size;
  const float* query = (const float*)d_in[0];
  const float* key_  = (const float*)d_in[1];
  const float* value = (const float*)d_in[2];
  const float* Wq = (const float*)d_in[3];
  const float* bq = (const float*)d_in[4];
  const float* Wk = (const float*)d_in[5];
  const float* bk = (const float*)d_in[6];
  const float* Wv = (const float*)d_in[7];
  const float* bv = (const float*)d_in[8];
  const float* Wo = (const float*)d_in[9];
  const float* bo = (const float*)d_in[10];

  const size_t NX = NXC;                   // per converted input / activation
  const size_t NW = (size_t)1024 * 1024;   // per converted weight
  __hip_bfloat16* ws  = (__hip_bfloat16*)d_ws;
  __hip_bfloat16* xq  = ws;                // xq,xk,xv contiguous (3*NX)
  __hip_bfloat16* wqb = ws + 3 * NX;       // wq,wk,wv,wo contiguous (4*NW)
  __hip_bfloat16* qh  = wqb + 4 * NW;
  __hip_bfloat16* kh  = qh + NX;
  __hip_bfloat16* vtr = kh + NX;           // [b][h][dh][s]
  __hip_bfloat16* ao  = vtr + NX;          // [b][s][h*64+dh]
  // after proj, xq/xk/xv are dead: reuse for attention partials
  __hip_bfloat16* po = ws;                 // [2][b][s][h*64+dh]
  float* Mf = (float*)(ws + 2 * NX);       // [2][32][2048]
  float* Lf = Mf + 131072;

  static bool attr_done = false;
  (void)attr_done;  // keep launch idempotent: call every time (cheap)
  hipFuncSetAttribute((const void*)proj256,
                      hipFuncAttributeMaxDynamicSharedMemorySize, 131072);

  cvt_inputs<<<dim3(2048, 3), 256, 0, stream>>>(query, key_, value, xq);
  cvt_weights<<<dim3(512, 4), 256, 0, stream>>>(Wq, Wk, Wv, Wo, wqb);
  proj256<<<dim3(192), 512, 131072, stream>>>(
      xq, xq + NX, xq + 2 * NX, wqb, wqb + NW, wqb + 2 * NW,
      bq, bk, bv, qh, kh, vtr);
  attn_partial<<<dim3(1024), 256, 0, stream>>>(qh, kh, vtr, po, Mf, Lf);
  attn_merge<<<dim3(2048), 256, 0, stream>>>(po, Mf, Lf, ao);
  out_proj<<<dim3(8, 32), 256, 0, stream>>>(ao, wqb + 3 * NW, bo, (float*)d_out);
}

// Round 5
// 241.813 us; speedup vs baseline: 1.3228x; 1.0185x over previous
//
#include <hip/hip_runtime.h>
#include <hip/hip_bf16.h>
#include <stdint.h>
#include <stddef.h>

// MHA forward, B=2 S=2048 D=1024 H=16 Dh=64, bf16 MFMA pipeline.
// cvt_all(fp32->bf16, one kernel) -> proj QKV (single dispatch, m97-exact
// 128^2/BK=64 single-buffer GEMM, XCD-chunked; V stored transposed per head;
// Q pre-scaled by log2e/sqrt(Dh)) -> flash attention kv-split x2 (32x32 MFMA,
// swapped QK^T and swapped PV, in-register softmax, cvt_pk+permlane32,
// defer-max, setprio, 4 blocks/CU) -> merge -> output proj (fp32 out).

typedef __attribute__((ext_vector_type(8))) short short8;   // 8 x bf16
typedef __attribute__((ext_vector_type(4))) float f32x4;    // 16x16 MFMA C/D
typedef __attribute__((ext_vector_type(16))) float f32x16;  // 32x32 MFMA C/D
typedef __attribute__((ext_vector_type(4))) unsigned short usv4;

#define DEVFN static __device__ __forceinline__

constexpr float LOG2E = 1.44269504088896340736f;
constexpr size_t NXC = 4194304;   // 4096*1024 elements
constexpr size_t NWC = 1048576;   // 1024*1024 elements

DEVFN f32x4 mfma16(short8 a, short8 b, f32x4 c) {
  return __builtin_amdgcn_mfma_f32_16x16x32_bf16(a, b, c, 0, 0, 0);
}

DEVFN f32x16 mfma32(short8 a, short8 b, f32x16 c) {
  return __builtin_amdgcn_mfma_f32_32x32x16_bf16(a, b, c, 0, 0, 0);
}

// async global->LDS, 16B per lane. Dest must be linear in lane id.
DEVFN void gload_lds16(const void* g, void* l) {
  __builtin_amdgcn_global_load_lds(
      (const __attribute__((address_space(1))) unsigned int*)g,
      (__attribute__((address_space(3))) unsigned int*)l, 16, 0, 0);
}

DEVFN unsigned short f2bf(float x) {
  union { __hip_bfloat16 h; unsigned short u; } cv;
  cv.h = __float2bfloat16(x);
  return cv.u;
}

DEVFN float bf2f(unsigned short u) {
  union { unsigned int i; float f; } cv;
  cv.i = ((unsigned int)u) << 16;
  return cv.f;
}

DEVFN unsigned cvt_pk(float lo, float hi) {   // u32 = {bf16(lo), bf16(hi)<<16}
  unsigned r;
  asm("v_cvt_pk_bf16_f32 %0, %1, %2" : "=v"(r) : "v"(lo), "v"(hi));
  return r;
}

DEVFN short8 cvt8(const float* s) {
  float4 a = *(const float4*)(s);
  float4 b = *(const float4*)(s + 4);
  short8 o;
  o[0] = (short)f2bf(a.x); o[1] = (short)f2bf(a.y);
  o[2] = (short)f2bf(a.z); o[3] = (short)f2bf(a.w);
  o[4] = (short)f2bf(b.x); o[5] = (short)f2bf(b.y);
  o[6] = (short)f2bf(b.z); o[7] = (short)f2bf(b.w);
  return o;
}

// ------- fp32 -> bf16 conversion, all 7 tensors, one kernel -------
// dst is contiguous: [3 x NXC inputs][4 x NWC weights]. 8192 blocks exactly.

__global__ __launch_bounds__(256) void cvt_all(
    const float* __restrict__ s0, const float* __restrict__ s1,
    const float* __restrict__ s2, const float* __restrict__ w0,
    const float* __restrict__ w1, const float* __restrict__ w2,
    const float* __restrict__ w3, __hip_bfloat16* __restrict__ dst) {
  const size_t e = ((size_t)blockIdx.x * 256 + threadIdx.x) * 8;
  const float* s;
  size_t off;
  if (e < 3 * NXC) {
    const int which = (int)(e / NXC);
    s = (which == 0) ? s0 : ((which == 1) ? s1 : s2);
    off = e - (size_t)which * NXC;
  } else {
    const size_t ew = e - 3 * NXC;
    const int which = (int)(ew / NWC);
    s = (which == 0) ? w0 : (which == 1) ? w1 : (which == 2) ? w2 : w3;
    off = ew - (size_t)which * NWC;
  }
  *(short8*)(dst + e) = cvt8(s + off);
}

// ------- 128x128 NT GEMM core (K=1024, BK=64, single-buffer, m97-exact) ----
// C[m][n] = sum_k A[m][k] * W[n][k]; 4 waves in 2x2, each 64x64 (4x4 frags).

DEVFN void gemm_core64(const __hip_bfloat16* __restrict__ A,
                       const __hip_bfloat16* __restrict__ W,
                       __hip_bfloat16* As, __hip_bfloat16* Bs,
                       int mBase, int nBase, f32x4 (&acc)[4][4]) {
  const int t = threadIdx.x;
  const int lane = t & 63;
  const int w = t >> 6;
  const int wr = w >> 1, wc = w & 1;
  const int c = lane & 15, g = lane >> 4;
  const int srow = t >> 3, sslot = t & 7;

  for (int kt = 0; kt < 16; ++kt) {
    const int k0 = kt * 64;
    __syncthreads();  // previous iteration's frag reads done
#pragma unroll
    for (int i = 0; i < 4; ++i) {
      const int r = srow + 32 * i;
      gload_lds16(A + (size_t)(mBase + r) * 1024 + k0 + sslot * 8,
                  As + r * 64 + sslot * 8);
      gload_lds16(W + (size_t)(nBase + r) * 1024 + k0 + sslot * 8,
                  Bs + r * 64 + sslot * 8);
    }
    __syncthreads();  // compiler emits vmcnt(0) drain before barrier

    short8 af[4][2], bfr[4][2];
#pragma unroll
    for (int m = 0; m < 4; ++m)
#pragma unroll
      for (int kk = 0; kk < 2; ++kk)
        af[m][kk] = *(const short8*)(As + (64 * wr + 16 * m + c) * 64 + kk * 32 + g * 8);
#pragma unroll
    for (int n = 0; n < 4; ++n)
#pragma unroll
      for (int kk = 0; kk < 2; ++kk)
        bfr[n][kk] = *(const short8*)(Bs + (64 * wc + 16 * n + c) * 64 + kk * 32 + g * 8);
#pragma unroll
    for (int kk = 0; kk < 2; ++kk)
#pragma unroll
      for (int m = 0; m < 4; ++m)
#pragma unroll
        for (int n = 0; n < 4; ++n)
          acc[m][n] = mfma16(af[m][kk], bfr[n][kk], acc[m][n]);
  }
}

// ---- QKV projection, ONE dispatch: 768 blocks = 3z x 8nt x 32mt ----
// XCD-chunked bijective swizzle: each XCD owns 96 consecutive sids
// (z-major, then nt, then mt) so its W panels (<=768KB) stay in its L2.

__global__ __launch_bounds__(256, 3) void proj_qkv(
    const __hip_bfloat16* __restrict__ xq,
    const __hip_bfloat16* __restrict__ wqb,
    const float* __restrict__ bq, const float* __restrict__ bk,
    const float* __restrict__ bv,
    __hip_bfloat16* __restrict__ qh, __hip_bfloat16* __restrict__ kh,
    __hip_bfloat16* __restrict__ vtr) {
  __shared__ __hip_bfloat16 As[128 * 64];
  __shared__ __hip_bfloat16 Bs[128 * 64];

  const int bid = blockIdx.x;
  const int sid = (bid & 7) * 96 + (bid >> 3);   // 768 = 8 XCD x 96
  const int z = sid >> 8;                        // 0..2
  const int rem = sid & 255;
  const int nBase = (rem >> 5) * 128;
  const int mBase = (rem & 31) * 128;

  const __hip_bfloat16* A = xq + (size_t)z * NXC;
  const __hip_bfloat16* W = wqb + (size_t)z * NWC;
  const float* bias = (z == 0) ? bq : ((z == 1) ? bk : bv);

  f32x4 acc[4][4] = {};
  gemm_core64(A, W, As, Bs, mBase, nBase, acc);

  const int t = threadIdx.x;
  const int lane = t & 63;
  const int w = t >> 6;
  const int wr = w >> 1, wc = w & 1;
  const int c = lane & 15, g = lane >> 4;

  if (z < 2) {
    __hip_bfloat16* O = (z == 0) ? qh : kh;
    // Q: 1/sqrt(Dh) * log2(e), so softmax is pure exp2
    const float scale = (z == 0) ? (0.125f * LOG2E) : 1.0f;
#pragma unroll
    for (int m = 0; m < 4; ++m) {
#pragma unroll
      for (int n = 0; n < 4; ++n) {
        const int row0 = mBase + 64 * wr + 16 * m + 4 * g;
        const int col = nBase + 64 * wc + 16 * n + c;
        const float bb = bias[col];
#pragma unroll
        for (int r = 0; r < 4; ++r)
          O[(size_t)(row0 + r) * 1024 + col] =
              __float2bfloat16((acc[m][n][r] + bb) * scale);
      }
    }
  } else {
    // V stored transposed per head: vtr[((b*16+h)*64+dh)*2048 + s]
#pragma unroll
    for (int m = 0; m < 4; ++m) {
#pragma unroll
      for (int n = 0; n < 4; ++n) {
        const int row0 = mBase + 64 * wr + 16 * m + 4 * g;  // global (b,s) row
        const int col = nBase + 64 * wc + 16 * n + c;       // d = h*64+dh
        const int bb = row0 >> 11;        // batch
        const int s0 = row0 & 2047;       // seq pos (4 consecutive)
        const float bv_ = bias[col];
        usv4 pk;
#pragma unroll
        for (int r = 0; r < 4; ++r) pk[r] = f2bf(acc[m][n][r] + bv_);
        *(usv4*)(vtr + ((size_t)(bb * 1024 + col)) * 2048 + s0) = pk;
      }
    }
  }
}

// ---------------- output projection (fp32 out + bias) ----------------

__global__ __launch_bounds__(256, 3) void out_proj(
    const __hip_bfloat16* __restrict__ ao, const __hip_bfloat16* __restrict__ wo,
    const float* __restrict__ bo, float* __restrict__ out) {
  __shared__ __hip_bfloat16 As[128 * 64];
  __shared__ __hip_bfloat16 Bs[128 * 64];

  const int bid = blockIdx.x;
  const int sid = (bid & 7) * 32 + (bid >> 3);   // 256 = 8 XCD x 32
  const int nBase = (sid >> 5) * 128;
  const int mBase = (sid & 31) * 128;

  f32x4 acc[4][4] = {};
  gemm_core64(ao, wo, As, Bs, mBase, nBase, acc);

  const int t = threadIdx.x;
  const int lane = t & 63;
  const int w = t >> 6;
  const int wr = w >> 1, wc = w & 1;
  const int c = lane & 15, g = lane >> 4;
#pragma unroll
  for (int m = 0; m < 4; ++m) {
#pragma unroll
    for (int n = 0; n < 4; ++n) {
      const int row0 = mBase + 64 * wr + 16 * m + 4 * g;
      const int col = nBase + 64 * wc + 16 * n + c;
      const float bb = bo[col];
#pragma unroll
      for (int r = 0; r < 4; ++r)
        out[(size_t)(row0 + r) * 1024 + col] = acc[m][n][r] + bb;
    }
  }
}

// ---------------- flash attention, kv-split x2, 32x32 MFMA ----------------
// grid: 1024 flat = (16 qtiles, 32 bh, 2 kv-halves), XCD-swizzled.
// 4 blocks/CU (LB 256,4) -> whole grid co-resident in one round.
// 4 waves; lane's q = lane&31 for accS (QK^T swapped) AND accO (PV swapped).
// KV tile 64, dbuf + counted vmcnt(4). P via cvt_pk + permlane32_swap.

__global__ __launch_bounds__(256, 4) void attn_partial(
    const __hip_bfloat16* __restrict__ qh, const __hip_bfloat16* __restrict__ kh,
    const __hip_bfloat16* __restrict__ vtr, __hip_bfloat16* __restrict__ po,
    float* __restrict__ Mbuf, float* __restrict__ Lbuf) {
  __shared__ __hip_bfloat16 Ks[2][64 * 64];   // [kv][d], slot-swizzled
  __shared__ __hip_bfloat16 Vs[2][64 * 64];   // [d][kv], slot-swizzled

  const int t = threadIdx.x;
  const int fid = blockIdx.x;
  const int xcd = fid & 7, idx = fid >> 3;
  const int bh = xcd * 4 + (idx & 3);
  const int qt = (idx >> 2) & 15;
  const int half = idx >> 6;
  const int b = bh >> 4, h = bh & 15;
  const int lane = t & 63;
  const int w = t >> 6;
  const int q32 = lane & 31;
  const int hi = lane >> 5;
  const int r7 = lane & 7;
  const size_t base = ((size_t)b * 2048) * 1024 + (size_t)h * 64;   // qh/kh/po
  const size_t vbase = ((size_t)(b * 1024 + h * 64)) * 2048;        // vtr
  const int halfBase = half * 1024;
  const int qrow = qt * 128 + 32 * w + q32;

  // Q B-fragments: qf[s] = Q[qrow][16s + 8hi .. +8) (pre-scaled by log2e/8)
  short8 qf[4];
#pragma unroll
  for (int s = 0; s < 4; ++s)
    qf[s] = *(const short8*)(qh + base + (size_t)qrow * 1024 + s * 16 + hi * 8);

  f32x16 accO[2];
#pragma unroll
  for (int jj = 0; jj < 2; ++jj) accO[jj] = (f32x16)(0.0f);
  float mreg = -1e30f, lreg = 0.f;

  const int srow = t >> 3, sslot = t & 7;

  auto STAGE = [&](int tile, int bufsel) {
    const int kbase = halfBase + tile * 64;
#pragma unroll
    for (int ii = 0; ii < 2; ++ii) {
      const int row = srow + 32 * ii;
      const int ss = sslot ^ (row & 7);   // source-side swizzle (involution)
      gload_lds16(kh + base + (size_t)(kbase + row) * 1024 + ss * 8,
                  &Ks[bufsel][row * 64 + sslot * 8]);
      gload_lds16(vtr + vbase + (size_t)row * 2048 + kbase + ss * 8,
                  &Vs[bufsel][row * 64 + sslot * 8]);
    }
  };

  STAGE(0, 0);

  for (int tt = 0; tt < 16; ++tt) {
    const int cur = tt & 1;
    if (tt < 15) {
      STAGE(tt + 1, cur ^ 1);
      asm volatile("s_waitcnt vmcnt(4)" ::: "memory");
    } else {
      asm volatile("s_waitcnt vmcnt(0)" ::: "memory");
    }
    __builtin_amdgcn_s_barrier();
    asm volatile("" ::: "memory");

    // QK^T swapped: A = K rows (kv), B = Q cols (q)
    f32x16 accS[2];
#pragma unroll
    for (int sub = 0; sub < 2; ++sub) accS[sub] = (f32x16)(0.0f);
    __builtin_amdgcn_s_setprio(1);
#pragma unroll
    for (int sub = 0; sub < 2; ++sub) {
      const int row = 32 * sub + q32;
#pragma unroll
      for (int s = 0; s < 4; ++s) {
        const int slot = (2 * s + hi) ^ r7;
        const short8 kf = *(const short8*)(&Ks[cur][row * 64 + slot * 8]);
        accS[sub] = mfma32(kf, qf[s], accS[sub]);
      }
    }
    __builtin_amdgcn_s_setprio(0);

    // online softmax, fully in-lane
    float pm[4] = {-1e30f, -1e30f, -1e30f, -1e30f};
#pragma unroll
    for (int sub = 0; sub < 2; ++sub)
#pragma unroll
      for (int rg = 0; rg < 16; ++rg) pm[rg & 3] = fmaxf(pm[rg & 3], accS[sub][rg]);
    float pmax = fmaxf(fmaxf(pm[0], pm[1]), fmaxf(pm[2], pm[3]));
    pmax = fmaxf(pmax, __shfl_xor(pmax, 32, 64));

    if (!__all(pmax - mreg <= 11.0f)) {   // defer-max (T13)
      const float mn = fmaxf(mreg, pmax);
      const float corr = exp2f(mreg - mn);
      mreg = mn;
      lreg *= corr;
#pragma unroll
      for (int jj = 0; jj < 2; ++jj)
#pragma unroll
        for (int rg = 0; rg < 16; ++rg) accO[jj][rg] *= corr;
    }

    float rs[4] = {0.f, 0.f, 0.f, 0.f};
#pragma unroll
    for (int sub = 0; sub < 2; ++sub)
#pragma unroll
      for (int rg = 0; rg < 16; ++rg) {
        const float p = exp2f(accS[sub][rg] - mreg);
        accS[sub][rg] = p;
        rs[rg & 3] += p;
      }
    float rsum = (rs[0] + rs[1]) + (rs[2] + rs[3]);
    rsum += __shfl_xor(rsum, 32, 64);
    lreg += rsum;

    // P -> PV B-fragments via cvt_pk + permlane32_swap
    short8 pb[2][2];
#pragma unroll
    for (int sub = 0; sub < 2; ++sub)
#pragma unroll
      for (int t2 = 0; t2 < 2; ++t2) {
        unsigned a  = cvt_pk(accS[sub][8 * t2 + 0], accS[sub][8 * t2 + 1]);
        unsigned a2 = cvt_pk(accS[sub][8 * t2 + 2], accS[sub][8 * t2 + 3]);
        unsigned bb = cvt_pk(accS[sub][8 * t2 + 4], accS[sub][8 * t2 + 5]);
        unsigned b2 = cvt_pk(accS[sub][8 * t2 + 6], accS[sub][8 * t2 + 7]);
        asm("v_permlane32_swap_b32 %0, %1" : "+v"(a), "+v"(bb));
        asm("v_permlane32_swap_b32 %0, %1" : "+v"(a2), "+v"(b2));
        union { unsigned u[4]; short8 v; } uu;
        uu.u[0] = a; uu.u[1] = a2; uu.u[2] = bb; uu.u[3] = b2;
        pb[sub][t2] = uu.v;
      }

    // PV swapped: A = V^T rows (d), B = P cols (q) -> accO col = q (in-lane)
    __builtin_amdgcn_s_setprio(1);
#pragma unroll
    for (int jj = 0; jj < 2; ++jj) {
      const int dl = 32 * jj + q32;
#pragma unroll
      for (int sub = 0; sub < 2; ++sub)
#pragma unroll
        for (int t2 = 0; t2 < 2; ++t2) {
          const int kslot = (4 * sub + 2 * t2 + hi) ^ r7;
          const short8 vf = *(const short8*)(&Vs[cur][dl * 64 + kslot * 8]);
          accO[jj] = mfma32(vf, pb[sub][t2], accO[jj]);
        }
    }
    __builtin_amdgcn_s_setprio(0);

    asm volatile("s_waitcnt lgkmcnt(0)" ::: "memory");
    __builtin_amdgcn_s_barrier();
  }

  // epilogue: normalized partial O (bf16) + per-row m,l
  const float linv = 1.0f / lreg;
#pragma unroll
  for (int jj = 0; jj < 2; ++jj)
#pragma unroll
    for (int s = 0; s < 4; ++s) {
      usv4 pk;
#pragma unroll
      for (int r = 0; r < 4; ++r) pk[r] = f2bf(accO[jj][4 * s + r] * linv);
      *(usv4*)(po + (size_t)half * NXC + base + (size_t)qrow * 1024 +
               32 * jj + 8 * s + 4 * hi) = pk;
    }
  if (lane < 32) {
    const int off = half * 65536 + bh * 2048 + qrow;
    Mbuf[off] = mreg;
    Lbuf[off] = lreg;
  }
}

// ---------------- merge the two kv-half partials ----------------

__global__ __launch_bounds__(256) void attn_merge(
    const __hip_bfloat16* __restrict__ po, const float* __restrict__ Mbuf,
    const float* __restrict__ Lbuf, __hip_bfloat16* __restrict__ ao) {
  const size_t e = ((size_t)blockIdx.x * 256 + threadIdx.x) * 8;
  const int srow = (int)(e >> 10);
  const int d0 = (int)(e & 1023);
  const int b = srow >> 11, s = srow & 2047;
  const int h = d0 >> 6;
  const int idx = (b * 16 + h) * 2048 + s;
  const float m0 = Mbuf[idx], m1 = Mbuf[65536 + idx];
  const float l0 = Lbuf[idx], l1 = Lbuf[65536 + idx];
  const float Mx = fmaxf(m0, m1);
  float w0 = exp2f(m0 - Mx) * l0;
  float w1 = exp2f(m1 - Mx) * l1;
  const float inv = 1.0f / (w0 + w1);
  w0 *= inv; w1 *= inv;
  const short8 x0 = *(const short8*)(po + e);
  const short8 x1 = *(const short8*)(po + NXC + e);
  short8 o;
#pragma unroll
  for (int j = 0; j < 8; ++j) {
    const float v = w0 * bf2f((unsigned short)x0[j]) +
                    w1 * bf2f((unsigned short)x1[j]);
    o[j] = (short)f2bf(v);
  }
  *(short8*)(ao + e) = o;
}

// ---------------- launch ----------------

extern "C" void kernel_launch(void* const* d_in, const int* in_sizes, int n_in,
                              void* d_out, int out_size, void* d_ws, size_t ws_size,
                              hipStream_t stream) {
  (void)in_sizes; (void)n_in; (void)out_size; (void)ws_size;
  const float* query = (const float*)d_in[0];
  const float* key_  = (const float*)d_in[1];
  const float* value = (const float*)d_in[2];
  const float* Wq = (const float*)d_in[3];
  const float* bq = (const float*)d_in[4];
  const float* Wk = (const float*)d_in[5];
  const float* bk = (const float*)d_in[6];
  const float* Wv = (const float*)d_in[7];
  const float* bv = (const float*)d_in[8];
  const float* Wo = (const float*)d_in[9];
  const float* bo = (const float*)d_in[10];

  __hip_bfloat16* ws  = (__hip_bfloat16*)d_ws;
  __hip_bfloat16* xq  = ws;                // xq,xk,xv contiguous (3*NXC)
  __hip_bfloat16* wqb = ws + 3 * NXC;      // wq,wk,wv,wo contiguous (4*NWC)
  __hip_bfloat16* qh  = wqb + 4 * NWC;
  __hip_bfloat16* kh  = qh + NXC;
  __hip_bfloat16* vtr = kh + NXC;          // [b][h][dh][s]
  __hip_bfloat16* ao  = vtr + NXC;         // [b][s][h*64+dh]
  // after proj, xq/xk/xv are dead: reuse for attention partials
  __hip_bfloat16* po = ws;                 // [2][b][s][h*64+dh]
  float* Mf = (float*)(ws + 2 * NXC);      // [2][32][2048]
  float* Lf = Mf + 131072;
  // total ws use: 64 MiB

  cvt_all<<<dim3(8192), 256, 0, stream>>>(query, key_, value,
                                          Wq, Wk, Wv, Wo, xq);
  proj_qkv<<<dim3(768), 256, 0, stream>>>(xq, wqb, bq, bk, bv, qh, kh, vtr);
  attn_partial<<<dim3(1024), 256, 0, stream>>>(qh, kh, vtr, po, Mf, Lf);
  attn_merge<<<dim3(2048), 256, 0, stream>>>(po, Mf, Lf, ao);
  out_proj<<<dim3(256), 256, 0, stream>>>(ao, wqb + 3 * NWC, bo, (float*)d_out);
}